// Round 2
// baseline (953.568 us; speedup 1.0000x reference)
//
#include <hip/hip_runtime.h>
#include <hip/hip_bf16.h>
#include <cstdint>
#include <cstddef>

typedef __bf16 bf16;
typedef __attribute__((ext_vector_type(8))) __bf16 bf16x8;
typedef __attribute__((ext_vector_type(4))) float f32x4;

#define BB 8
#define LL 4096
#define DMODEL 256
#define DINNER 1024
#define MT (BB*LL)
#define NCH 64               // chunks per sequence
#define LCH (LL/NCH)         // 64 steps per chunk

// ---------------- sentinel when ws is too small ----------------
__global__ __launch_bounds__(256) void k_wsfail(float* out, int n){
    int i = blockIdx.x*256 + threadIdx.x;
    if (i < n) out[i] = 1e9f;
}

// ---------------- cast three fp32 weight arrays to bf16 ----------------
__global__ __launch_bounds__(256) void k_cast3(const float* __restrict__ s1, const float* __restrict__ s2,
                                               const float* __restrict__ s3,
                                               bf16* __restrict__ o1, bf16* __restrict__ o2, bf16* __restrict__ o3,
                                               int n1, int n2, int n3){
    int i = blockIdx.x*256 + threadIdx.x;
    if (i < n1) o1[i] = (bf16)s1[i];
    else if (i < n1+n2) o2[i-n1] = (bf16)s2[i-n1];
    else if (i < n1+n2+n3) o3[i-n1-n2] = (bf16)s3[i-n1-n2];
}

// ---------------- RMSNorm: x[rows][256] -> h bf16 ----------------
__global__ __launch_bounds__(256) void k_rms(const float* __restrict__ x, const float* __restrict__ w,
                                             bf16* __restrict__ h){
    int m = blockIdx.x, t = threadIdx.x;
    float v = x[(size_t)m*DMODEL + t];
    float s = v*v;
    #pragma unroll
    for (int o=1;o<64;o<<=1) s += __shfl_xor(s, o, 64);
    __shared__ float ps[4];
    if ((t&63)==0) ps[t>>6] = s;
    __syncthreads();
    float tot = ps[0]+ps[1]+ps[2]+ps[3];
    float inv = rsqrtf(tot*(1.0f/DMODEL) + 1e-5f);
    h[(size_t)m*DMODEL + t] = (bf16)(v*inv*w[t]);
}

// ---------------- bf16 MFMA GEMM: C[M][N] = A[M][K] * Bw[N][K]^T ----------------
// 128x128 tile, BK=32, 4 waves (2x2 of 64x64), 16x16x32 MFMA.
// MODE 0: bf16 C1[row*N+col]          (x_proj, with NMASK)
// MODE 1: bf16 split halves: col<1024 -> C1, else C2 (both stride 1024)  (in_proj)
// MODE 2: fp32 Cf[row*N+col] = v + res[row*N+col]   (out_proj + residual)
template<int MODE, bool NMASK>
__global__ __launch_bounds__(256) void k_gemm(const bf16* __restrict__ A, const bf16* __restrict__ Bw,
                                              bf16* __restrict__ C1, bf16* __restrict__ C2,
                                              float* __restrict__ Cf, const float* __restrict__ res,
                                              int M, int N, int K){
    __shared__ __align__(16) bf16 As[128][40];   // +8 pad
    __shared__ __align__(16) bf16 Bs[128][40];
    const int tid  = threadIdx.x;
    const int m0   = blockIdx.x*128, n0 = blockIdx.y*128;
    const int wave = tid>>6, lane = tid&63;
    const int wr   = wave>>1, wc = wave&1;       // 2x2 wave grid of 64x64 subtiles
    const int fr   = lane&15, kg = lane>>4;      // fragment row/col, k-group
    const int srow = tid>>1, shalf = tid&1;      // staging: 2 threads per row, 16 elems

    f32x4 acc[4][4] = {};

    for (int kt=0; kt<K; kt+=32){
        { // stage A tile [128][32]
            const bf16* g = A + (size_t)(m0+srow)*K + kt + shalf*16;
            uint4 v0 = *(const uint4*)g;
            uint4 v1 = *(const uint4*)(g+8);
            *(uint4*)&As[srow][shalf*16]   = v0;
            *(uint4*)&As[srow][shalf*16+8] = v1;
        }
        { // stage B tile [128][32] (rows are output cols)
            uint4 v0 = make_uint4(0,0,0,0), v1 = make_uint4(0,0,0,0);
            int nr = n0 + srow;
            if (!NMASK || nr < N){
                const bf16* g = Bw + (size_t)nr*K + kt + shalf*16;
                v0 = *(const uint4*)g; v1 = *(const uint4*)(g+8);
            }
            *(uint4*)&Bs[srow][shalf*16]   = v0;
            *(uint4*)&Bs[srow][shalf*16+8] = v1;
        }
        __syncthreads();
        bf16x8 af[4], bfv[4];
        #pragma unroll
        for (int i=0;i<4;i++) af[i]  = *(const bf16x8*)&As[wr*64 + i*16 + fr][kg*8];
        #pragma unroll
        for (int j=0;j<4;j++) bfv[j] = *(const bf16x8*)&Bs[wc*64 + j*16 + fr][kg*8];
        #pragma unroll
        for (int i=0;i<4;i++)
            #pragma unroll
            for (int j=0;j<4;j++)
                acc[i][j] = __builtin_amdgcn_mfma_f32_16x16x32_bf16(af[i], bfv[j], acc[i][j], 0,0,0);
        __syncthreads();
    }
    // epilogue: C/D layout col=lane&15, row=(lane>>4)*4+reg   [m89]
    #pragma unroll
    for (int i=0;i<4;i++)
        #pragma unroll
        for (int j=0;j<4;j++)
            #pragma unroll
            for (int r=0;r<4;r++){
                int row = m0 + wr*64 + i*16 + kg*4 + r;
                int col = n0 + wc*64 + j*16 + fr;
                float v = acc[i][j][r];
                if (MODE==0){
                    if (!NMASK || col < N) C1[(size_t)row*N + col] = (bf16)v;
                } else if (MODE==1){
                    bf16* dst = (col < 1024) ? C1 : C2;
                    dst[(size_t)row*1024 + (col & 1023)] = (bf16)v;
                } else {
                    size_t o = (size_t)row*N + col;
                    Cf[o] = v + res[o];
                }
            }
}

// ---------------- depthwise causal conv (k=4) + SiLU: xc -> xa ----------------
__global__ __launch_bounds__(256) void k_conv(const bf16* __restrict__ xc, const float* __restrict__ cw,
                                              const float* __restrict__ cb, bf16* __restrict__ xa){
    int i = blockIdx.x*256 + threadIdx.x;     // over rows*DINNER
    int d = i & (DINNER-1);
    int m = i >> 10;
    int t = m & (LL-1);
    float s = cb[d];
    #pragma unroll
    for (int j=0;j<4;j++){
        int tt = t + j - 3;
        if (tt >= 0) s += (float)xc[(size_t)(m+j-3)*DINNER + d] * cw[d*4+j];
    }
    float sig = 1.f/(1.f+__expf(-s));
    xa[(size_t)m*DINNER + d] = (bf16)(s*sig);
}

__device__ __forceinline__ float softplus_f(float a){
    return fmaxf(a, 0.f) + __logf(1.f + __expf(-fabsf(a)));
}

// ---------------- scan pass 1: per-chunk affine combine (P,S) ----------------
// recomputes dt from x_dbl on the fly (no dt buffer)
__global__ __launch_bounds__(256) void k_pass1(const bf16* __restrict__ xa, const bf16* __restrict__ xdbl,
                                               const float* __restrict__ Alog, const float* __restrict__ dtw,
                                               const float* __restrict__ dtb, float* __restrict__ PSf){
    int d = blockIdx.x*256 + threadIdx.x;     // 0..1023
    int c = blockIdx.y, b = blockIdx.z;       // local batch
    float An[16], W[16];
    #pragma unroll
    for (int n=0;n<16;n++){ An[n] = -__expf(Alog[d*16+n]); W[n] = dtw[d*16+n]; }
    float bias = dtb[d];
    float P[16], S[16];
    #pragma unroll
    for (int n=0;n<16;n++){ P[n]=1.f; S[n]=0.f; }
    int mbase = b*LL + c*LCH;
    for (int s=0;s<LCH;s++){
        int m = mbase + s;
        const bf16* xr = xdbl + (size_t)m*48;
        float a = bias;
        #pragma unroll
        for (int r=0;r<16;r++) a += (float)xr[r]*W[r];
        float dtv = softplus_f(a);
        float xv  = (float)xa[(size_t)m*DINNER + d];
        float dx  = dtv*xv;
        #pragma unroll
        for (int n=0;n<16;n++){
            float dA = __expf(dtv*An[n]);
            float Bv = (float)xr[16+n];
            S[n] = dA*S[n] + dx*Bv;
            P[n] *= dA;
        }
    }
    size_t base = ((size_t)(b*NCH + c)*DINNER + d)*16;
    #pragma unroll
    for (int n=0;n<16;n++) *(float2*)&PSf[(base+n)*2] = make_float2(P[n], S[n]);
}

// ---------------- scan pass 2: cross-chunk prefix, Hi written in-place (.x slot) ----------------
__global__ __launch_bounds__(256) void k_pass2(float* __restrict__ PSf){
    int i = blockIdx.x*256 + threadIdx.x;     // nb*16384
    int b   = i >> 14;
    int low = i & 16383;
    float h = 0.f;
    for (int c=0;c<NCH;c++){
        size_t idx = ((size_t)(b*NCH + c)*16384 + low)*2;
        float2 ps = *(const float2*)&PSf[idx];
        PSf[idx] = h;                          // h at chunk start
        h = ps.x*h + ps.y;
    }
}

// ---------------- scan pass 3: replay chunk, y + skip + SiLU(z) gate ----------------
__global__ __launch_bounds__(256) void k_pass3(const bf16* __restrict__ xa, const bf16* __restrict__ xdbl,
                                               const bf16* __restrict__ z, const float* __restrict__ Alog,
                                               const float* __restrict__ dtw, const float* __restrict__ dtb,
                                               const float* __restrict__ Dp, const float* __restrict__ PSf,
                                               bf16* __restrict__ y){
    int d = blockIdx.x*256 + threadIdx.x;
    int c = blockIdx.y, b = blockIdx.z;
    float An[16], W[16], h[16];
    #pragma unroll
    for (int n=0;n<16;n++){ An[n] = -__expf(Alog[d*16+n]); W[n] = dtw[d*16+n]; }
    float bias = dtb[d];
    size_t hbase = ((size_t)(b*NCH + c)*DINNER + d)*16;
    #pragma unroll
    for (int n=0;n<16;n++) h[n] = PSf[(hbase+n)*2];
    float Dd = Dp[d];
    int mbase = b*LL + c*LCH;
    for (int s=0;s<LCH;s++){
        int m = mbase + s;
        const bf16* xr = xdbl + (size_t)m*48;
        float a = bias;
        #pragma unroll
        for (int r=0;r<16;r++) a += (float)xr[r]*W[r];
        float dtv = softplus_f(a);
        float xv  = (float)xa[(size_t)m*DINNER + d];
        float dx  = dtv*xv;
        float yv = 0.f;
        #pragma unroll
        for (int n=0;n<16;n++){
            float dA = __expf(dtv*An[n]);
            float Bv = (float)xr[16+n];
            float Cv = (float)xr[32+n];
            h[n] = dA*h[n] + dx*Bv;
            yv += h[n]*Cv;
        }
        float zv = (float)z[(size_t)m*DINNER + d];
        float g  = zv/(1.f+__expf(-zv));
        y[(size_t)m*DINNER + d] = (bf16)((yv + xv*Dd)*g);
    }
}

extern "C" void kernel_launch(void* const* d_in, const int* in_sizes, int n_in,
                              void* d_out, int out_size, void* d_ws, size_t ws_size,
                              hipStream_t stream) {
    const float* x     = (const float*)d_in[0];
    const float* normw = (const float*)d_in[1];
    const float* w_in  = (const float*)d_in[2];
    const float* convw = (const float*)d_in[3];
    const float* convb = (const float*)d_in[4];
    const float* w_xp  = (const float*)d_in[5];
    const float* dtw   = (const float*)d_in[6];
    const float* dtb   = (const float*)d_in[7];
    const float* Alog  = (const float*)d_in[8];
    const float* Dp    = (const float*)d_in[9];
    const float* w_out = (const float*)d_in[10];

    const size_t WB    = ((size_t)2048*256 + 48*1024 + 256*1024)*2;
    const size_t WB_AL = (WB + 255) & ~(size_t)255;
    auto need = [WB_AL](int nb)->size_t{
        size_t rows = (size_t)nb*LL;
        size_t big  = rows*DINNER*2;                       // xc_y / z / xa, bf16
        size_t xd   = ((rows*48*2) + 255) & ~(size_t)255;  // x_dbl bf16
        size_t ps   = (size_t)nb*NCH*DINNER*16*8;          // float2 (h bf16 overlaps)
        return WB_AL + 3*big + xd + ps;
    };
    int NB = 0;
    const int cand[4] = {8,4,2,1};
    for (int k=0;k<4;k++) if (need(cand[k]) <= ws_size){ NB = cand[k]; break; }
    if (!NB){
        k_wsfail<<<(out_size+255)/256, 256, 0, stream>>>((float*)d_out, out_size);
        return;
    }

    char* ws = (char*)d_ws;
    bf16* win_b  = (bf16*)ws;
    bf16* wxp_b  = (bf16*)(ws + (size_t)2048*256*2);
    bf16* wout_b = (bf16*)(ws + (size_t)2048*256*2 + (size_t)48*1024*2);

    size_t rows  = (size_t)NB*LL;
    size_t big   = rows*DINNER*2;
    size_t xd_al = ((rows*48*2) + 255) & ~(size_t)255;
    char*  ar    = ws + WB_AL;
    bf16*  xcy   = (bf16*)ar;            // xc, later reused for y
    bf16*  zb    = (bf16*)(ar + big);
    bf16*  xab   = (bf16*)(ar + 2*big);
    bf16*  xdb   = (bf16*)(ar + 3*big);
    float* psf   = (float*)(ar + 3*big + xd_al);
    bf16*  hb    = (bf16*)psf;           // h overlaps PS (disjoint lifetimes)

    k_cast3<<<(2048*256 + 48*1024 + 256*1024)/256, 256, 0, stream>>>(
        w_in, w_xp, w_out, win_b, wxp_b, wout_b, 2048*256, 48*1024, 256*1024);

    for (int b0=0; b0<BB; b0+=NB){
        const float* xb = x + (size_t)b0*LL*DMODEL;
        float*       ob = (float*)d_out + (size_t)b0*LL*DMODEL;
        // RMSNorm
        k_rms<<<(int)rows, 256, 0, stream>>>(xb, normw, hb);
        // in_proj -> xc, z
        k_gemm<1,false><<<dim3((int)rows/128, 16), 256, 0, stream>>>(
            hb, win_b, xcy, zb, nullptr, nullptr, (int)rows, 2048, 256);
        // conv + SiLU -> xa
        k_conv<<<(int)(rows*DINNER/256), 256, 0, stream>>>(xcy, convw, convb, xab);
        // x_proj -> x_dbl (N=48 masked)
        k_gemm<0,true><<<dim3((int)rows/128, 1), 256, 0, stream>>>(
            xab, wxp_b, xdb, nullptr, nullptr, nullptr, (int)rows, 48, 1024);
        // chunked selective scan
        k_pass1<<<dim3(4, NCH, NB), 256, 0, stream>>>(xab, xdb, Alog, dtw, dtb, psf);
        k_pass2<<<NB*64, 256, 0, stream>>>(psf);
        k_pass3<<<dim3(4, NCH, NB), 256, 0, stream>>>(xab, xdb, zb, Alog, dtw, dtb, Dp, psf, xcy);
        // out_proj + residual -> fp32 out
        k_gemm<2,false><<<dim3((int)rows/128, 2), 256, 0, stream>>>(
            xcy, wout_b, nullptr, nullptr, ob, xb, (int)rows, 256, 1024);
    }
}

// Round 3
// 824.629 us; speedup vs baseline: 1.1564x; 1.1564x over previous
//
#include <hip/hip_runtime.h>
#include <hip/hip_bf16.h>
#include <cstdint>
#include <cstddef>

typedef __bf16 bf16;
typedef __attribute__((ext_vector_type(8))) __bf16 bf16x8;
typedef __attribute__((ext_vector_type(4))) float f32x4;

#define BB 8
#define LL 4096
#define DMODEL 256
#define DINNER 1024
#define MT (BB*LL)
#define NCH 64               // chunks per sequence
#define LCH (LL/NCH)         // 64 steps per chunk

// ---------------- sentinel when ws is too small ----------------
__global__ __launch_bounds__(256) void k_wsfail(float* out, int n){
    int i = blockIdx.x*256 + threadIdx.x;
    if (i < n) out[i] = 1e9f;
}

// ---------------- cast three fp32 weight arrays to bf16 ----------------
__global__ __launch_bounds__(256) void k_cast3(const float* __restrict__ s1, const float* __restrict__ s2,
                                               const float* __restrict__ s3,
                                               bf16* __restrict__ o1, bf16* __restrict__ o2, bf16* __restrict__ o3,
                                               int n1, int n2, int n3){
    int i = blockIdx.x*256 + threadIdx.x;
    if (i < n1) o1[i] = (bf16)s1[i];
    else if (i < n1+n2) o2[i-n1] = (bf16)s2[i-n1];
    else if (i < n1+n2+n3) o3[i-n1-n2] = (bf16)s3[i-n1-n2];
}

// ---------------- RMSNorm: x[rows][256] -> h bf16 ----------------
__global__ __launch_bounds__(256) void k_rms(const float* __restrict__ x, const float* __restrict__ w,
                                             bf16* __restrict__ h){
    int m = blockIdx.x, t = threadIdx.x;
    float v = x[(size_t)m*DMODEL + t];
    float s = v*v;
    #pragma unroll
    for (int o=1;o<64;o<<=1) s += __shfl_xor(s, o, 64);
    __shared__ float ps[4];
    if ((t&63)==0) ps[t>>6] = s;
    __syncthreads();
    float tot = ps[0]+ps[1]+ps[2]+ps[3];
    float inv = rsqrtf(tot*(1.0f/DMODEL) + 1e-5f);
    h[(size_t)m*DMODEL + t] = (bf16)(v*inv*w[t]);
}

// ---------------- bf16 MFMA GEMM: C[M][N] = A[M][K] * Bw[N][K]^T ----------------
// MODE 0: bf16 C1[row*N+col]                                (x_proj, NMASK)
// MODE 1: bf16 split halves col<1024 -> C1 else C2           (in_proj)
// MODE 2: fp32 Cf = v + res                                  (out_proj + residual)
template<int MODE, bool NMASK>
__global__ __launch_bounds__(256) void k_gemm(const bf16* __restrict__ A, const bf16* __restrict__ Bw,
                                              bf16* __restrict__ C1, bf16* __restrict__ C2,
                                              float* __restrict__ Cf, const float* __restrict__ res,
                                              int M, int N, int K){
    __shared__ __align__(16) bf16 As[128][40];   // +8 pad
    __shared__ __align__(16) bf16 Bs[128][40];
    const int tid  = threadIdx.x;
    const int m0   = blockIdx.x*128, n0 = blockIdx.y*128;
    const int wave = tid>>6, lane = tid&63;
    const int wr   = wave>>1, wc = wave&1;
    const int fr   = lane&15, kg = lane>>4;
    const int srow = tid>>1, shalf = tid&1;

    f32x4 acc[4][4] = {};

    for (int kt=0; kt<K; kt+=32){
        {
            const bf16* g = A + (size_t)(m0+srow)*K + kt + shalf*16;
            uint4 v0 = *(const uint4*)g;
            uint4 v1 = *(const uint4*)(g+8);
            *(uint4*)&As[srow][shalf*16]   = v0;
            *(uint4*)&As[srow][shalf*16+8] = v1;
        }
        {
            uint4 v0 = make_uint4(0,0,0,0), v1 = make_uint4(0,0,0,0);
            int nr = n0 + srow;
            if (!NMASK || nr < N){
                const bf16* g = Bw + (size_t)nr*K + kt + shalf*16;
                v0 = *(const uint4*)g; v1 = *(const uint4*)(g+8);
            }
            *(uint4*)&Bs[srow][shalf*16]   = v0;
            *(uint4*)&Bs[srow][shalf*16+8] = v1;
        }
        __syncthreads();
        bf16x8 af[4], bfv[4];
        #pragma unroll
        for (int i=0;i<4;i++) af[i]  = *(const bf16x8*)&As[wr*64 + i*16 + fr][kg*8];
        #pragma unroll
        for (int j=0;j<4;j++) bfv[j] = *(const bf16x8*)&Bs[wc*64 + j*16 + fr][kg*8];
        #pragma unroll
        for (int i=0;i<4;i++)
            #pragma unroll
            for (int j=0;j<4;j++)
                acc[i][j] = __builtin_amdgcn_mfma_f32_16x16x32_bf16(af[i], bfv[j], acc[i][j], 0,0,0);
        __syncthreads();
    }
    #pragma unroll
    for (int i=0;i<4;i++)
        #pragma unroll
        for (int j=0;j<4;j++)
            #pragma unroll
            for (int r=0;r<4;r++){
                int row = m0 + wr*64 + i*16 + kg*4 + r;
                int col = n0 + wc*64 + j*16 + fr;
                float v = acc[i][j][r];
                if (MODE==0){
                    if (!NMASK || col < N) C1[(size_t)row*N + col] = (bf16)v;
                } else if (MODE==1){
                    bf16* dst = (col < 1024) ? C1 : C2;
                    dst[(size_t)row*1024 + (col & 1023)] = (bf16)v;
                } else {
                    size_t o = (size_t)row*N + col;
                    Cf[o] = v + res[o];
                }
            }
}

// ---------------- depthwise causal conv (k=4) + SiLU: xc -> xa ----------------
__global__ __launch_bounds__(256) void k_conv(const bf16* __restrict__ xc, const float* __restrict__ cw,
                                              const float* __restrict__ cb, bf16* __restrict__ xa){
    int i = blockIdx.x*256 + threadIdx.x;
    int d = i & (DINNER-1);
    int m = i >> 10;
    int t = m & (LL-1);
    float s = cb[d];
    #pragma unroll
    for (int j=0;j<4;j++){
        int tt = t + j - 3;
        if (tt >= 0) s += (float)xc[(size_t)(m+j-3)*DINNER + d] * cw[d*4+j];
    }
    float sig = 1.f/(1.f+__expf(-s));
    xa[(size_t)m*DINNER + d] = (bf16)(s*sig);
}

__device__ __forceinline__ float softplus_f(float a){
    return fmaxf(a, 0.f) + __logf(1.f + __expf(-fabsf(a)));
}

// ---------------- dt precompute: dt[m][d] = softplus(xdbl[m][0:16]·dtw[d] + dtb[d]) ----------------
// writes into the dead xc buffer (consumed by conv already)
__global__ __launch_bounds__(256) void k_dt(const bf16* __restrict__ xdbl, const float* __restrict__ dtw,
                                            const float* __restrict__ dtb, bf16* __restrict__ dty){
    int i = blockIdx.x*256 + threadIdx.x;
    int d = i & (DINNER-1);
    int m = i >> 10;                          // constant across the block (256 | 1024)
    __shared__ float xs[16];
    if (threadIdx.x < 16) xs[threadIdx.x] = (float)xdbl[(size_t)m*48 + threadIdx.x];
    __syncthreads();
    const float4* wp = (const float4*)(dtw + d*16);
    float a = dtb[d];
    #pragma unroll
    for (int q=0;q<4;q++){
        float4 w4 = wp[q];
        a = fmaf(xs[q*4+0], w4.x, a);
        a = fmaf(xs[q*4+1], w4.y, a);
        a = fmaf(xs[q*4+2], w4.z, a);
        a = fmaf(xs[q*4+3], w4.w, a);
    }
    dty[(size_t)m*DINNER + d] = (bf16)softplus_f(a);
}

// ---------------- scan pass 1: per-chunk affine combine (P,S) ----------------
__global__ __launch_bounds__(256) void k_pass1(const bf16* __restrict__ dty, const bf16* __restrict__ xa,
                                               const bf16* __restrict__ xdbl, const float* __restrict__ Alog,
                                               float* __restrict__ PSf){
    int d = blockIdx.x*256 + threadIdx.x;
    int c = blockIdx.y, b = blockIdx.z;
    int mbase = b*LL + c*LCH;

    __shared__ __align__(16) bf16 xs[LCH][16];      // B block of x_dbl
    if (threadIdx.x < 128){
        int row = threadIdx.x>>1, part = threadIdx.x&1;
        *(uint4*)&xs[row][part*8] = *(const uint4*)(xdbl + (size_t)(mbase+row)*48 + 16 + part*8);
    }
    float An[16];
    {
        const float4* Ap = (const float4*)(Alog + d*16);
        #pragma unroll
        for (int q=0;q<4;q++){
            float4 a4 = Ap[q];
            An[q*4+0] = -__expf(a4.x); An[q*4+1] = -__expf(a4.y);
            An[q*4+2] = -__expf(a4.z); An[q*4+3] = -__expf(a4.w);
        }
    }
    __syncthreads();

    float S[16];
    #pragma unroll
    for (int n=0;n<16;n++) S[n]=0.f;
    float sdt = 0.f;

    for (int s=0;s<LCH;s++){
        int m = mbase + s;
        float dtv = (float)dty[(size_t)m*DINNER + d];
        float xv  = (float)xa [(size_t)m*DINNER + d];
        float dx  = dtv*xv;
        bf16x8 b0 = *(const bf16x8*)&xs[s][0];
        bf16x8 b1 = *(const bf16x8*)&xs[s][8];
        #pragma unroll
        for (int n=0;n<8;n++){
            float dA = __expf(dtv*An[n]);
            S[n] = fmaf(dA, S[n], dx*(float)b0[n]);
        }
        #pragma unroll
        for (int n=0;n<8;n++){
            float dA = __expf(dtv*An[8+n]);
            S[8+n] = fmaf(dA, S[8+n], dx*(float)b1[n]);
        }
        sdt += dtv;
    }
    size_t base = ((size_t)(b*NCH + c)*DINNER + d)*16;
    #pragma unroll
    for (int n=0;n<16;n++)
        *(float2*)&PSf[(base+n)*2] = make_float2(__expf(An[n]*sdt), S[n]);
}

// ---------------- scan pass 2: cross-chunk prefix, h written in-place (.x slot) ----------------
__global__ __launch_bounds__(256) void k_pass2(float* __restrict__ PSf){
    int i = blockIdx.x*256 + threadIdx.x;
    int b   = i >> 14;
    int low = i & 16383;
    float h = 0.f;
    for (int c=0;c<NCH;c++){
        size_t idx = ((size_t)(b*NCH + c)*16384 + low)*2;
        float2 ps = *(const float2*)&PSf[idx];
        PSf[idx] = h;
        h = ps.x*h + ps.y;
    }
}

// ---------------- scan pass 3: replay chunk, y + skip + SiLU(z) gate ----------------
// dty holds dt on entry; y is written OVER it (same [m][d] slot, same thread, read-before-write)
__global__ __launch_bounds__(256) void k_pass3(bf16* __restrict__ dty, const bf16* __restrict__ xa,
                                               const bf16* __restrict__ xdbl, const bf16* __restrict__ z,
                                               const float* __restrict__ Alog, const float* __restrict__ Dp,
                                               const float* __restrict__ PSf){
    int d = blockIdx.x*256 + threadIdx.x;
    int c = blockIdx.y, b = blockIdx.z;
    int mbase = b*LL + c*LCH;

    __shared__ __align__(16) bf16 xs[LCH][32];      // B,C block of x_dbl
    {
        int row = threadIdx.x>>2, part = threadIdx.x&3;
        *(uint4*)&xs[row][part*8] = *(const uint4*)(xdbl + (size_t)(mbase+row)*48 + 16 + part*8);
    }
    float An[16];
    {
        const float4* Ap = (const float4*)(Alog + d*16);
        #pragma unroll
        for (int q=0;q<4;q++){
            float4 a4 = Ap[q];
            An[q*4+0] = -__expf(a4.x); An[q*4+1] = -__expf(a4.y);
            An[q*4+2] = -__expf(a4.z); An[q*4+3] = -__expf(a4.w);
        }
    }
    float h[16];
    size_t hbase = ((size_t)(b*NCH + c)*DINNER + d)*16;
    #pragma unroll
    for (int n=0;n<16;n++) h[n] = PSf[(hbase+n)*2];
    float Dd = Dp[d];
    __syncthreads();

    for (int s=0;s<LCH;s++){
        int m = mbase + s;
        size_t off = (size_t)m*DINNER + d;
        float dtv = (float)dty[off];
        float xv  = (float)xa[off];
        float zv  = (float)z[off];
        float dx  = dtv*xv;
        bf16x8 b0 = *(const bf16x8*)&xs[s][0];
        bf16x8 b1 = *(const bf16x8*)&xs[s][8];
        bf16x8 c0 = *(const bf16x8*)&xs[s][16];
        bf16x8 c1 = *(const bf16x8*)&xs[s][24];
        float yv = 0.f;
        #pragma unroll
        for (int n=0;n<8;n++){
            float dA = __expf(dtv*An[n]);
            h[n] = fmaf(dA, h[n], dx*(float)b0[n]);
            yv   = fmaf(h[n], (float)c0[n], yv);
        }
        #pragma unroll
        for (int n=0;n<8;n++){
            float dA = __expf(dtv*An[8+n]);
            h[8+n] = fmaf(dA, h[8+n], dx*(float)b1[n]);
            yv     = fmaf(h[8+n], (float)c1[n], yv);
        }
        float g = zv/(1.f+__expf(-zv));
        dty[off] = (bf16)((yv + xv*Dd)*g);
    }
}

extern "C" void kernel_launch(void* const* d_in, const int* in_sizes, int n_in,
                              void* d_out, int out_size, void* d_ws, size_t ws_size,
                              hipStream_t stream) {
    const float* x     = (const float*)d_in[0];
    const float* normw = (const float*)d_in[1];
    const float* w_in  = (const float*)d_in[2];
    const float* convw = (const float*)d_in[3];
    const float* convb = (const float*)d_in[4];
    const float* w_xp  = (const float*)d_in[5];
    const float* dtw   = (const float*)d_in[6];
    const float* dtb   = (const float*)d_in[7];
    const float* Alog  = (const float*)d_in[8];
    const float* Dp    = (const float*)d_in[9];
    const float* w_out = (const float*)d_in[10];

    const size_t WB    = ((size_t)2048*256 + 48*1024 + 256*1024)*2;
    const size_t WB_AL = (WB + 255) & ~(size_t)255;
    auto need = [WB_AL](int nb)->size_t{
        size_t rows = (size_t)nb*LL;
        size_t big  = rows*DINNER*2;                       // xc/dt/y, z, xa (bf16)
        size_t xd   = ((rows*48*2) + 255) & ~(size_t)255;  // x_dbl bf16
        size_t ps   = (size_t)nb*NCH*DINNER*16*8;          // float2 (h bf16 overlaps)
        return WB_AL + 3*big + xd + ps;
    };
    int NB = 0;
    const int cand[4] = {8,4,2,1};
    for (int k=0;k<4;k++) if (need(cand[k]) <= ws_size){ NB = cand[k]; break; }
    if (!NB){
        k_wsfail<<<(out_size+255)/256, 256, 0, stream>>>((float*)d_out, out_size);
        return;
    }

    char* ws = (char*)d_ws;
    bf16* win_b  = (bf16*)ws;
    bf16* wxp_b  = (bf16*)(ws + (size_t)2048*256*2);
    bf16* wout_b = (bf16*)(ws + (size_t)2048*256*2 + (size_t)48*1024*2);

    size_t rows  = (size_t)NB*LL;
    size_t big   = rows*DINNER*2;
    size_t xd_al = ((rows*48*2) + 255) & ~(size_t)255;
    char*  ar    = ws + WB_AL;
    bf16*  xcy   = (bf16*)ar;            // xc -> dt -> y (sequential lifetimes)
    bf16*  zb    = (bf16*)(ar + big);
    bf16*  xab   = (bf16*)(ar + 2*big);
    bf16*  xdb   = (bf16*)(ar + 3*big);
    float* psf   = (float*)(ar + 3*big + xd_al);
    bf16*  hb    = (bf16*)psf;           // h overlaps PS (disjoint lifetimes)

    k_cast3<<<(2048*256 + 48*1024 + 256*1024)/256, 256, 0, stream>>>(
        w_in, w_xp, w_out, win_b, wxp_b, wout_b, 2048*256, 48*1024, 256*1024);

    for (int b0=0; b0<BB; b0+=NB){
        const float* xb = x + (size_t)b0*LL*DMODEL;
        float*       ob = (float*)d_out + (size_t)b0*LL*DMODEL;
        k_rms<<<(int)rows, 256, 0, stream>>>(xb, normw, hb);
        k_gemm<1,false><<<dim3((int)rows/128, 16), 256, 0, stream>>>(
            hb, win_b, xcy, zb, nullptr, nullptr, (int)rows, 2048, 256);
        k_conv<<<(int)(rows*DINNER/256), 256, 0, stream>>>(xcy, convw, convb, xab);
        k_gemm<0,true><<<dim3((int)rows/128, 1), 256, 0, stream>>>(
            xab, wxp_b, xdb, nullptr, nullptr, nullptr, (int)rows, 48, 1024);
        k_dt<<<(int)(rows*DINNER/256), 256, 0, stream>>>(xdb, dtw, dtb, xcy);
        k_pass1<<<dim3(4, NCH, NB), 256, 0, stream>>>(xcy, xab, xdb, Alog, psf);
        k_pass2<<<NB*64, 256, 0, stream>>>(psf);
        k_pass3<<<dim3(4, NCH, NB), 256, 0, stream>>>(xcy, xab, xdb, zb, Alog, Dp, psf);
        k_gemm<2,false><<<dim3((int)rows/128, 2), 256, 0, stream>>>(
            xcy, wout_b, nullptr, nullptr, ob, xb, (int)rows, 256, 1024);
    }
}

// Round 4
// 762.815 us; speedup vs baseline: 1.2501x; 1.0810x over previous
//
#include <hip/hip_runtime.h>
#include <hip/hip_bf16.h>
#include <cstdint>
#include <cstddef>

typedef __bf16 bf16;
typedef __attribute__((ext_vector_type(8))) __bf16 bf16x8;
typedef __attribute__((ext_vector_type(4))) float f32x4;

#define BB 8
#define LL 4096
#define DMODEL 256
#define DINNER 1024
#define MT (BB*LL)

__constant__ float LOGT[16] = {
    0.0f, 0.6931471806f, 1.0986122887f, 1.3862943611f,
    1.6094379124f, 1.7917594692f, 1.9459101091f, 2.0794415417f,
    2.1972245773f, 2.3025850930f, 2.3978952728f, 2.4849066498f,
    2.5649493575f, 2.6390573296f, 2.7080502011f, 2.7725887222f};

// ---------------- sentinel when ws is too small ----------------
__global__ __launch_bounds__(256) void k_wsfail(float* out, int n){
    int i = blockIdx.x*256 + threadIdx.x;
    if (i < n) out[i] = 1e9f;
}

// ---------------- cast three fp32 weight arrays to bf16 ----------------
__global__ __launch_bounds__(256) void k_cast3(const float* __restrict__ s1, const float* __restrict__ s2,
                                               const float* __restrict__ s3,
                                               bf16* __restrict__ o1, bf16* __restrict__ o2, bf16* __restrict__ o3,
                                               int n1, int n2, int n3){
    int i = blockIdx.x*256 + threadIdx.x;
    if (i < n1) o1[i] = (bf16)s1[i];
    else if (i < n1+n2) o2[i-n1] = (bf16)s2[i-n1];
    else if (i < n1+n2+n3) o3[i-n1-n2] = (bf16)s3[i-n1-n2];
}

// ---------------- RMSNorm ----------------
__global__ __launch_bounds__(256) void k_rms(const float* __restrict__ x, const float* __restrict__ w,
                                             bf16* __restrict__ h){
    int m = blockIdx.x, t = threadIdx.x;
    float v = x[(size_t)m*DMODEL + t];
    float s = v*v;
    #pragma unroll
    for (int o=1;o<64;o<<=1) s += __shfl_xor(s, o, 64);
    __shared__ float ps[4];
    if ((t&63)==0) ps[t>>6] = s;
    __syncthreads();
    float tot = ps[0]+ps[1]+ps[2]+ps[3];
    float inv = rsqrtf(tot*(1.0f/DMODEL) + 1e-5f);
    h[(size_t)m*DMODEL + t] = (bf16)(v*inv*w[t]);
}

// ---------------- bf16 MFMA GEMM ----------------
template<int MODE, bool NMASK>
__global__ __launch_bounds__(256) void k_gemm(const bf16* __restrict__ A, const bf16* __restrict__ Bw,
                                              bf16* __restrict__ C1, bf16* __restrict__ C2,
                                              float* __restrict__ Cf, const float* __restrict__ res,
                                              int M, int N, int K){
    __shared__ __align__(16) bf16 As[128][40];
    __shared__ __align__(16) bf16 Bs[128][40];
    const int tid  = threadIdx.x;
    const int m0   = blockIdx.x*128, n0 = blockIdx.y*128;
    const int wave = tid>>6, lane = tid&63;
    const int wr   = wave>>1, wc = wave&1;
    const int fr   = lane&15, kg = lane>>4;
    const int srow = tid>>1, shalf = tid&1;

    f32x4 acc[4][4] = {};

    for (int kt=0; kt<K; kt+=32){
        {
            const bf16* g = A + (size_t)(m0+srow)*K + kt + shalf*16;
            uint4 v0 = *(const uint4*)g;
            uint4 v1 = *(const uint4*)(g+8);
            *(uint4*)&As[srow][shalf*16]   = v0;
            *(uint4*)&As[srow][shalf*16+8] = v1;
        }
        {
            uint4 v0 = make_uint4(0,0,0,0), v1 = make_uint4(0,0,0,0);
            int nr = n0 + srow;
            if (!NMASK || nr < N){
                const bf16* g = Bw + (size_t)nr*K + kt + shalf*16;
                v0 = *(const uint4*)g; v1 = *(const uint4*)(g+8);
            }
            *(uint4*)&Bs[srow][shalf*16]   = v0;
            *(uint4*)&Bs[srow][shalf*16+8] = v1;
        }
        __syncthreads();
        bf16x8 af[4], bfv[4];
        #pragma unroll
        for (int i=0;i<4;i++) af[i]  = *(const bf16x8*)&As[wr*64 + i*16 + fr][kg*8];
        #pragma unroll
        for (int j=0;j<4;j++) bfv[j] = *(const bf16x8*)&Bs[wc*64 + j*16 + fr][kg*8];
        #pragma unroll
        for (int i=0;i<4;i++)
            #pragma unroll
            for (int j=0;j<4;j++)
                acc[i][j] = __builtin_amdgcn_mfma_f32_16x16x32_bf16(af[i], bfv[j], acc[i][j], 0,0,0);
        __syncthreads();
    }
    #pragma unroll
    for (int i=0;i<4;i++)
        #pragma unroll
        for (int j=0;j<4;j++)
            #pragma unroll
            for (int r=0;r<4;r++){
                int row = m0 + wr*64 + i*16 + kg*4 + r;
                int col = n0 + wc*64 + j*16 + fr;
                float v = acc[i][j][r];
                if (MODE==0){
                    if (!NMASK || col < N) C1[(size_t)row*N + col] = (bf16)v;
                } else if (MODE==1){
                    bf16* dst = (col < 1024) ? C1 : C2;
                    dst[(size_t)row*1024 + (col & 1023)] = (bf16)v;
                } else {
                    size_t o = (size_t)row*N + col;
                    Cf[o] = v + res[o];
                }
            }
}

// ---------------- depthwise causal conv (k=4) + SiLU ----------------
__global__ __launch_bounds__(256) void k_conv(const bf16* __restrict__ xc, const float* __restrict__ cw,
                                              const float* __restrict__ cb, bf16* __restrict__ xa){
    int i = blockIdx.x*256 + threadIdx.x;
    int d = i & (DINNER-1);
    int m = i >> 10;
    int t = m & (LL-1);
    float s = cb[d];
    #pragma unroll
    for (int j=0;j<4;j++){
        int tt = t + j - 3;
        if (tt >= 0) s += (float)xc[(size_t)(m+j-3)*DINNER + d] * cw[d*4+j];
    }
    float sig = 1.f/(1.f+__expf(-s));
    xa[(size_t)m*DINNER + d] = (bf16)(s*sig);
}

__device__ __forceinline__ float softplus_f(float a){
    return fmaxf(a, 0.f) + __logf(1.f + __expf(-fabsf(a)));
}

// pw[n] = p^(n+1), depth-4 multiply tree
__device__ __forceinline__ void powchain(float p, float* pw){
    pw[0]=p;
    pw[1]=pw[0]*pw[0];  pw[2]=pw[1]*pw[0];  pw[3]=pw[1]*pw[1];
    pw[4]=pw[1]*pw[2];  pw[5]=pw[2]*pw[2];  pw[6]=pw[2]*pw[3];  pw[7]=pw[3]*pw[3];
    pw[8]=pw[3]*pw[4];  pw[9]=pw[4]*pw[4];  pw[10]=pw[4]*pw[5]; pw[11]=pw[5]*pw[5];
    pw[12]=pw[5]*pw[6]; pw[13]=pw[6]*pw[6]; pw[14]=pw[6]*pw[7]; pw[15]=pw[7]*pw[7];
}

// ---------------- dt precompute into dead xc buffer ----------------
__global__ __launch_bounds__(256) void k_dt(const bf16* __restrict__ xdbl, const float* __restrict__ dtw,
                                            const float* __restrict__ dtb, bf16* __restrict__ dty){
    int i = blockIdx.x*256 + threadIdx.x;
    int d = i & (DINNER-1);
    int m = i >> 10;
    __shared__ float xs[16];
    if (threadIdx.x < 16) xs[threadIdx.x] = (float)xdbl[(size_t)m*48 + threadIdx.x];
    __syncthreads();
    const float4* wp = (const float4*)(dtw + d*16);
    float a = dtb[d];
    #pragma unroll
    for (int q=0;q<4;q++){
        float4 w4 = wp[q];
        a = fmaf(xs[q*4+0], w4.x, a);
        a = fmaf(xs[q*4+1], w4.y, a);
        a = fmaf(xs[q*4+2], w4.z, a);
        a = fmaf(xs[q*4+3], w4.w, a);
    }
    dty[(size_t)m*DINNER + d] = (bf16)softplus_f(a);
}

// ---------------- scan pass 1: per-chunk (P,S), SoA output ----------------
template<int LCHT>
__global__ __launch_bounds__(256) void k_pass1(const bf16* __restrict__ dty, const bf16* __restrict__ xa,
                                               const bf16* __restrict__ xdbl, const float* __restrict__ Alog,
                                               float* __restrict__ Pp, float* __restrict__ Sp, int nch){
    int d = blockIdx.x*256 + threadIdx.x;
    int c = blockIdx.y, b = blockIdx.z;
    int mbase = b*LL + c*LCHT;

    __shared__ __align__(16) bf16 xs[LCHT][16];
    if (threadIdx.x < LCHT*2){
        int row = threadIdx.x>>1, part = threadIdx.x&1;
        *(uint4*)&xs[row][part*8] = *(const uint4*)(xdbl + (size_t)(mbase+row)*48 + 16 + part*8);
    }
    // structured-A check: Alog[d][n] == log(n+1) ?
    bool st = true;
    float Ald[16];
    {
        const float4* Ap = (const float4*)(Alog + d*16);
        #pragma unroll
        for (int q=0;q<4;q++){
            float4 a4 = Ap[q];
            Ald[q*4+0]=a4.x; Ald[q*4+1]=a4.y; Ald[q*4+2]=a4.z; Ald[q*4+3]=a4.w;
        }
        #pragma unroll
        for (int n=0;n<16;n++) st = st && (fabsf(Ald[n]-LOGT[n]) < 1e-4f);
    }
    __syncthreads();

    float S[16];
    #pragma unroll
    for (int n=0;n<16;n++) S[n]=0.f;
    float sdt = 0.f;

    if (st){
        for (int s=0;s<LCHT;s++){
            int m = mbase + s;
            float dtv = (float)dty[(size_t)m*DINNER + d];
            float xv  = (float)xa [(size_t)m*DINNER + d];
            float dx  = dtv*xv;
            float pw[16];
            powchain(__expf(-dtv), pw);
            bf16x8 b0 = *(const bf16x8*)&xs[s][0];
            bf16x8 b1 = *(const bf16x8*)&xs[s][8];
            #pragma unroll
            for (int n=0;n<8;n++)  S[n]   = fmaf(pw[n],   S[n],   dx*(float)b0[n]);
            #pragma unroll
            for (int n=0;n<8;n++)  S[8+n] = fmaf(pw[8+n], S[8+n], dx*(float)b1[n]);
            sdt += dtv;
        }
    } else {
        float An[16];
        #pragma unroll
        for (int n=0;n<16;n++) An[n] = -__expf(Ald[n]);
        for (int s=0;s<LCHT;s++){
            int m = mbase + s;
            float dtv = (float)dty[(size_t)m*DINNER + d];
            float xv  = (float)xa [(size_t)m*DINNER + d];
            float dx  = dtv*xv;
            bf16x8 b0 = *(const bf16x8*)&xs[s][0];
            bf16x8 b1 = *(const bf16x8*)&xs[s][8];
            #pragma unroll
            for (int n=0;n<8;n++)  S[n]   = fmaf(__expf(dtv*An[n]),   S[n],   dx*(float)b0[n]);
            #pragma unroll
            for (int n=0;n<8;n++)  S[8+n] = fmaf(__expf(dtv*An[8+n]), S[8+n], dx*(float)b1[n]);
            sdt += dtv;
        }
    }
    size_t base = ((size_t)(b*nch + c)*DINNER + d)*16;
    float P[16];
    if (st){
        powchain(__expf(-sdt), P);
    } else {
        float An[16];
        #pragma unroll
        for (int n=0;n<16;n++) An[n] = -__expf(Ald[n]);
        #pragma unroll
        for (int n=0;n<16;n++) P[n] = __expf(An[n]*sdt);
    }
    #pragma unroll
    for (int q=0;q<4;q++){
        *(float4*)&Pp[base+q*4] = make_float4(P[q*4],P[q*4+1],P[q*4+2],P[q*4+3]);
        *(float4*)&Sp[base+q*4] = make_float4(S[q*4],S[q*4+1],S[q*4+2],S[q*4+3]);
    }
}

// ---------------- scan pass 2: cross-chunk prefix; h into P slot ----------------
__global__ __launch_bounds__(256) void k_pass2(float* __restrict__ Pp, float* __restrict__ Sp, int nch){
    int i = blockIdx.x*256 + threadIdx.x;
    int b   = i >> 14;
    int low = i & 16383;
    float h = 0.f;
    for (int c=0;c<nch;c++){
        size_t idx = (size_t)(b*nch + c)*16384 + low;
        float P = Pp[idx], S = Sp[idx];
        Pp[idx] = h;
        h = P*h + S;
    }
}

// ---------------- scan pass 3: replay; y over dt buffer ----------------
template<int LCHT>
__global__ __launch_bounds__(256) void k_pass3(bf16* __restrict__ dty, const bf16* __restrict__ xa,
                                               const bf16* __restrict__ xdbl, const bf16* __restrict__ z,
                                               const float* __restrict__ Alog, const float* __restrict__ Dp,
                                               const float* __restrict__ Pp, int nch){
    int d = blockIdx.x*256 + threadIdx.x;
    int c = blockIdx.y, b = blockIdx.z;
    int mbase = b*LL + c*LCHT;

    __shared__ __align__(16) bf16 xs[LCHT][32];
    if (threadIdx.x < LCHT*4){
        int row = threadIdx.x>>2, part = threadIdx.x&3;
        *(uint4*)&xs[row][part*8] = *(const uint4*)(xdbl + (size_t)(mbase+row)*48 + 16 + part*8);
    }
    bool st = true;
    float Ald[16];
    {
        const float4* Ap = (const float4*)(Alog + d*16);
        #pragma unroll
        for (int q=0;q<4;q++){
            float4 a4 = Ap[q];
            Ald[q*4+0]=a4.x; Ald[q*4+1]=a4.y; Ald[q*4+2]=a4.z; Ald[q*4+3]=a4.w;
        }
        #pragma unroll
        for (int n=0;n<16;n++) st = st && (fabsf(Ald[n]-LOGT[n]) < 1e-4f);
    }
    float h[16];
    size_t hbase = ((size_t)(b*nch + c)*DINNER + d)*16;
    #pragma unroll
    for (int q=0;q<4;q++){
        float4 h4 = *(const float4*)&Pp[hbase+q*4];
        h[q*4]=h4.x; h[q*4+1]=h4.y; h[q*4+2]=h4.z; h[q*4+3]=h4.w;
    }
    float Dd = Dp[d];
    __syncthreads();

    if (st){
        for (int s=0;s<LCHT;s++){
            int m = mbase + s;
            size_t off = (size_t)m*DINNER + d;
            float dtv = (float)dty[off];
            float xv  = (float)xa[off];
            float zv  = (float)z[off];
            float dx  = dtv*xv;
            float pw[16];
            powchain(__expf(-dtv), pw);
            bf16x8 b0 = *(const bf16x8*)&xs[s][0];
            bf16x8 b1 = *(const bf16x8*)&xs[s][8];
            bf16x8 c0 = *(const bf16x8*)&xs[s][16];
            bf16x8 c1 = *(const bf16x8*)&xs[s][24];
            float yv = 0.f;
            #pragma unroll
            for (int n=0;n<8;n++){
                h[n] = fmaf(pw[n], h[n], dx*(float)b0[n]);
                yv   = fmaf(h[n], (float)c0[n], yv);
            }
            #pragma unroll
            for (int n=0;n<8;n++){
                h[8+n] = fmaf(pw[8+n], h[8+n], dx*(float)b1[n]);
                yv     = fmaf(h[8+n], (float)c1[n], yv);
            }
            float g = zv/(1.f+__expf(-zv));
            dty[off] = (bf16)((yv + xv*Dd)*g);
        }
    } else {
        float An[16];
        #pragma unroll
        for (int n=0;n<16;n++) An[n] = -__expf(Ald[n]);
        for (int s=0;s<LCHT;s++){
            int m = mbase + s;
            size_t off = (size_t)m*DINNER + d;
            float dtv = (float)dty[off];
            float xv  = (float)xa[off];
            float zv  = (float)z[off];
            float dx  = dtv*xv;
            bf16x8 b0 = *(const bf16x8*)&xs[s][0];
            bf16x8 b1 = *(const bf16x8*)&xs[s][8];
            bf16x8 c0 = *(const bf16x8*)&xs[s][16];
            bf16x8 c1 = *(const bf16x8*)&xs[s][24];
            float yv = 0.f;
            #pragma unroll
            for (int n=0;n<8;n++){
                h[n] = fmaf(__expf(dtv*An[n]), h[n], dx*(float)b0[n]);
                yv   = fmaf(h[n], (float)c0[n], yv);
            }
            #pragma unroll
            for (int n=0;n<8;n++){
                h[8+n] = fmaf(__expf(dtv*An[8+n]), h[8+n], dx*(float)b1[n]);
                yv     = fmaf(h[8+n], (float)c1[n], yv);
            }
            float g = zv/(1.f+__expf(-zv));
            dty[off] = (bf16)((yv + xv*Dd)*g);
        }
    }
}

extern "C" void kernel_launch(void* const* d_in, const int* in_sizes, int n_in,
                              void* d_out, int out_size, void* d_ws, size_t ws_size,
                              hipStream_t stream) {
    const float* x     = (const float*)d_in[0];
    const float* normw = (const float*)d_in[1];
    const float* w_in  = (const float*)d_in[2];
    const float* convw = (const float*)d_in[3];
    const float* convb = (const float*)d_in[4];
    const float* w_xp  = (const float*)d_in[5];
    const float* dtw   = (const float*)d_in[6];
    const float* dtb   = (const float*)d_in[7];
    const float* Alog  = (const float*)d_in[8];
    const float* Dp    = (const float*)d_in[9];
    const float* w_out = (const float*)d_in[10];

    const size_t WB    = ((size_t)2048*256 + 48*1024 + 256*1024)*2;
    const size_t WB_AL = (WB + 255) & ~(size_t)255;
    auto need = [WB_AL](int nb, int nch)->size_t{
        size_t rows = (size_t)nb*LL;
        size_t big  = rows*DINNER*2;
        size_t xd   = ((rows*48*2) + 255) & ~(size_t)255;
        size_t ps   = (size_t)nb*nch*DINNER*16*8;     // P + S planes (fp32 each)
        return WB_AL + 3*big + xd + ps;
    };
    // preference: fewer phases first, then more chunks (parallelism)
    const int cands[8][2] = {{8,128},{8,64},{4,128},{4,64},{2,128},{2,64},{1,128},{1,64}};
    int NB = 0, NCHv = 0;
    for (int k=0;k<8;k++) if (need(cands[k][0], cands[k][1]) <= ws_size){ NB=cands[k][0]; NCHv=cands[k][1]; break; }
    if (!NB){
        k_wsfail<<<(out_size+255)/256, 256, 0, stream>>>((float*)d_out, out_size);
        return;
    }
    const int LCHv = LL/NCHv;

    char* ws = (char*)d_ws;
    bf16* win_b  = (bf16*)ws;
    bf16* wxp_b  = (bf16*)(ws + (size_t)2048*256*2);
    bf16* wout_b = (bf16*)(ws + (size_t)2048*256*2 + (size_t)48*1024*2);

    size_t rows  = (size_t)NB*LL;
    size_t big   = rows*DINNER*2;
    size_t xd_al = ((rows*48*2) + 255) & ~(size_t)255;
    char*  ar    = ws + WB_AL;
    bf16*  xcy   = (bf16*)ar;            // xc -> dt -> y
    bf16*  zb    = (bf16*)(ar + big);
    bf16*  xab   = (bf16*)(ar + 2*big);
    bf16*  xdb   = (bf16*)(ar + 3*big);
    float* Pp    = (float*)(ar + 3*big + xd_al);
    float* Sp    = Pp + (size_t)NB*NCHv*DINNER*16;
    bf16*  hb    = (bf16*)Pp;            // overlaps PS (disjoint lifetimes)

    k_cast3<<<(2048*256 + 48*1024 + 256*1024)/256, 256, 0, stream>>>(
        w_in, w_xp, w_out, win_b, wxp_b, wout_b, 2048*256, 48*1024, 256*1024);

    for (int b0=0; b0<BB; b0+=NB){
        const float* xb = x + (size_t)b0*LL*DMODEL;
        float*       ob = (float*)d_out + (size_t)b0*LL*DMODEL;
        k_rms<<<(int)rows, 256, 0, stream>>>(xb, normw, hb);
        k_gemm<1,false><<<dim3((int)rows/128, 16), 256, 0, stream>>>(
            hb, win_b, xcy, zb, nullptr, nullptr, (int)rows, 2048, 256);
        k_conv<<<(int)(rows*DINNER/256), 256, 0, stream>>>(xcy, convw, convb, xab);
        k_gemm<0,true><<<dim3((int)rows/128, 1), 256, 0, stream>>>(
            xab, wxp_b, xdb, nullptr, nullptr, nullptr, (int)rows, 48, 1024);
        k_dt<<<(int)(rows*DINNER/256), 256, 0, stream>>>(xdb, dtw, dtb, xcy);
        if (LCHv == 64){
            k_pass1<64><<<dim3(4, NCHv, NB), 256, 0, stream>>>(xcy, xab, xdb, Alog, Pp, Sp, NCHv);
            k_pass2<<<NB*64, 256, 0, stream>>>(Pp, Sp, NCHv);
            k_pass3<64><<<dim3(4, NCHv, NB), 256, 0, stream>>>(xcy, xab, xdb, zb, Alog, Dp, Pp, NCHv);
        } else {
            k_pass1<32><<<dim3(4, NCHv, NB), 256, 0, stream>>>(xcy, xab, xdb, Alog, Pp, Sp, NCHv);
            k_pass2<<<NB*64, 256, 0, stream>>>(Pp, Sp, NCHv);
            k_pass3<32><<<dim3(4, NCHv, NB), 256, 0, stream>>>(xcy, xab, xdb, zb, Alog, Dp, Pp, NCHv);
        }
        k_gemm<2,false><<<dim3((int)rows/128, 2), 256, 0, stream>>>(
            xcy, wout_b, nullptr, nullptr, ob, xb, (int)rows, 256, 1024);
    }
}

// Round 5
// 648.869 us; speedup vs baseline: 1.4696x; 1.1756x over previous
//
#include <hip/hip_runtime.h>
#include <hip/hip_bf16.h>
#include <cstdint>
#include <cstddef>

typedef __bf16 bf16;
typedef __attribute__((ext_vector_type(8))) __bf16 bf16x8;
typedef __attribute__((ext_vector_type(4))) float f32x4;

#define BB 8
#define LL 4096
#define DMODEL 256
#define DINNER 1024
#define MT (BB*LL)

__constant__ float LOGT[16] = {
    0.0f, 0.6931471806f, 1.0986122887f, 1.3862943611f,
    1.6094379124f, 1.7917594692f, 1.9459101091f, 2.0794415417f,
    2.1972245773f, 2.3025850930f, 2.3978952728f, 2.4849066498f,
    2.5649493575f, 2.6390573296f, 2.7080502011f, 2.7725887222f};

// ---------------- sentinel when ws is too small ----------------
__global__ __launch_bounds__(256) void k_wsfail(float* out, int n){
    int i = blockIdx.x*256 + threadIdx.x;
    if (i < n) out[i] = 1e9f;
}

// ---------------- cast three fp32 weight arrays to bf16 ----------------
__global__ __launch_bounds__(256) void k_cast3(const float* __restrict__ s1, const float* __restrict__ s2,
                                               const float* __restrict__ s3,
                                               bf16* __restrict__ o1, bf16* __restrict__ o2, bf16* __restrict__ o3,
                                               int n1, int n2, int n3){
    int i = blockIdx.x*256 + threadIdx.x;
    if (i < n1) o1[i] = (bf16)s1[i];
    else if (i < n1+n2) o2[i-n1] = (bf16)s2[i-n1];
    else if (i < n1+n2+n3) o3[i-n1-n2] = (bf16)s3[i-n1-n2];
}

// ---------------- RMSNorm ----------------
__global__ __launch_bounds__(256) void k_rms(const float* __restrict__ x, const float* __restrict__ w,
                                             bf16* __restrict__ h){
    int m = blockIdx.x, t = threadIdx.x;
    float v = x[(size_t)m*DMODEL + t];
    float s = v*v;
    #pragma unroll
    for (int o=1;o<64;o<<=1) s += __shfl_xor(s, o, 64);
    __shared__ float ps[4];
    if ((t&63)==0) ps[t>>6] = s;
    __syncthreads();
    float tot = ps[0]+ps[1]+ps[2]+ps[3];
    float inv = rsqrtf(tot*(1.0f/DMODEL) + 1e-5f);
    h[(size_t)m*DMODEL + t] = (bf16)(v*inv*w[t]);
}

// ---------------- bf16 MFMA GEMM ----------------
template<int MODE, bool NMASK>
__global__ __launch_bounds__(256) void k_gemm(const bf16* __restrict__ A, const bf16* __restrict__ Bw,
                                              bf16* __restrict__ C1, bf16* __restrict__ C2,
                                              float* __restrict__ Cf, const float* __restrict__ res,
                                              int M, int N, int K){
    __shared__ __align__(16) bf16 As[128][40];
    __shared__ __align__(16) bf16 Bs[128][40];
    const int tid  = threadIdx.x;
    const int m0   = blockIdx.x*128, n0 = blockIdx.y*128;
    const int wave = tid>>6, lane = tid&63;
    const int wr   = wave>>1, wc = wave&1;
    const int fr   = lane&15, kg = lane>>4;
    const int srow = tid>>1, shalf = tid&1;

    f32x4 acc[4][4] = {};

    for (int kt=0; kt<K; kt+=32){
        {
            const bf16* g = A + (size_t)(m0+srow)*K + kt + shalf*16;
            uint4 v0 = *(const uint4*)g;
            uint4 v1 = *(const uint4*)(g+8);
            *(uint4*)&As[srow][shalf*16]   = v0;
            *(uint4*)&As[srow][shalf*16+8] = v1;
        }
        {
            uint4 v0 = make_uint4(0,0,0,0), v1 = make_uint4(0,0,0,0);
            int nr = n0 + srow;
            if (!NMASK || nr < N){
                const bf16* g = Bw + (size_t)nr*K + kt + shalf*16;
                v0 = *(const uint4*)g; v1 = *(const uint4*)(g+8);
            }
            *(uint4*)&Bs[srow][shalf*16]   = v0;
            *(uint4*)&Bs[srow][shalf*16+8] = v1;
        }
        __syncthreads();
        bf16x8 af[4], bfv[4];
        #pragma unroll
        for (int i=0;i<4;i++) af[i]  = *(const bf16x8*)&As[wr*64 + i*16 + fr][kg*8];
        #pragma unroll
        for (int j=0;j<4;j++) bfv[j] = *(const bf16x8*)&Bs[wc*64 + j*16 + fr][kg*8];
        #pragma unroll
        for (int i=0;i<4;i++)
            #pragma unroll
            for (int j=0;j<4;j++)
                acc[i][j] = __builtin_amdgcn_mfma_f32_16x16x32_bf16(af[i], bfv[j], acc[i][j], 0,0,0);
        __syncthreads();
    }
    #pragma unroll
    for (int i=0;i<4;i++)
        #pragma unroll
        for (int j=0;j<4;j++)
            #pragma unroll
            for (int r=0;r<4;r++){
                int row = m0 + wr*64 + i*16 + kg*4 + r;
                int col = n0 + wc*64 + j*16 + fr;
                float v = acc[i][j][r];
                if (MODE==0){
                    if (!NMASK || col < N) C1[(size_t)row*N + col] = (bf16)v;
                } else if (MODE==1){
                    bf16* dst = (col < 1024) ? C1 : C2;
                    dst[(size_t)row*1024 + (col & 1023)] = (bf16)v;
                } else {
                    size_t o = (size_t)row*N + col;
                    Cf[o] = v + res[o];
                }
            }
}

// ---------------- depthwise causal conv (k=4) + SiLU, 8 d's/thread ----------------
__global__ __launch_bounds__(256) void k_conv(const bf16* __restrict__ xc, const float* __restrict__ cw,
                                              const float* __restrict__ cb, bf16* __restrict__ xa){
    int i  = blockIdx.x*256 + threadIdx.x;       // over rows*DINNER/8
    int dv = i & (DINNER/8 - 1);
    int m  = i >> 7;
    int t  = m & (LL-1);
    int d0 = dv*8;

    float4 w4[8];
    #pragma unroll
    for (int q=0;q<8;q++) w4[q] = *(const float4*)(cw + (size_t)(d0+q)*4);
    float acc[8];
    {
        float4 b0 = *(const float4*)(cb + d0);
        float4 b1 = *(const float4*)(cb + d0 + 4);
        acc[0]=b0.x; acc[1]=b0.y; acc[2]=b0.z; acc[3]=b0.w;
        acc[4]=b1.x; acc[5]=b1.y; acc[6]=b1.z; acc[7]=b1.w;
    }
    const bf16* base = xc + (size_t)m*DINNER + d0;
    if (t >= 3){
        #pragma unroll
        for (int j=0;j<4;j++){
            bf16x8 v = *(const bf16x8*)(base + (size_t)(j-3)*DINNER);
            acc[0]=fmaf((float)v[0], ((const float*)&w4[0])[j], acc[0]);
            acc[1]=fmaf((float)v[1], ((const float*)&w4[1])[j], acc[1]);
            acc[2]=fmaf((float)v[2], ((const float*)&w4[2])[j], acc[2]);
            acc[3]=fmaf((float)v[3], ((const float*)&w4[3])[j], acc[3]);
            acc[4]=fmaf((float)v[4], ((const float*)&w4[4])[j], acc[4]);
            acc[5]=fmaf((float)v[5], ((const float*)&w4[5])[j], acc[5]);
            acc[6]=fmaf((float)v[6], ((const float*)&w4[6])[j], acc[6]);
            acc[7]=fmaf((float)v[7], ((const float*)&w4[7])[j], acc[7]);
        }
    } else {
        #pragma unroll
        for (int j=0;j<4;j++){
            if (t + j - 3 >= 0){
                bf16x8 v = *(const bf16x8*)(base + (size_t)(j-3)*DINNER);
                #pragma unroll
                for (int q=0;q<8;q++)
                    acc[q]=fmaf((float)v[q], ((const float*)&w4[q])[j], acc[q]);
            }
        }
    }
    bf16x8 o;
    #pragma unroll
    for (int q=0;q<8;q++){
        float s = acc[q];
        o[q] = (bf16)(s/(1.f+__expf(-s)));
    }
    *(bf16x8*)(xa + (size_t)m*DINNER + d0) = o;
}

__device__ __forceinline__ float softplus_f(float a){
    return fmaxf(a, 0.f) + __logf(1.f + __expf(-fabsf(a)));
}

// pw[n] = p^(n+1), depth-4 multiply tree
__device__ __forceinline__ void powchain(float p, float* pw){
    pw[0]=p;
    pw[1]=pw[0]*pw[0];  pw[2]=pw[1]*pw[0];  pw[3]=pw[1]*pw[1];
    pw[4]=pw[1]*pw[2];  pw[5]=pw[2]*pw[2];  pw[6]=pw[2]*pw[3];  pw[7]=pw[3]*pw[3];
    pw[8]=pw[3]*pw[4];  pw[9]=pw[4]*pw[4];  pw[10]=pw[4]*pw[5]; pw[11]=pw[5]*pw[5];
    pw[12]=pw[5]*pw[6]; pw[13]=pw[6]*pw[6]; pw[14]=pw[6]*pw[7]; pw[15]=pw[7]*pw[7];
}

// ---------------- dt precompute: d-persistent threads, m-chunk loop ----------------
#define DTMCH 64
__global__ __launch_bounds__(256) void k_dt(const bf16* __restrict__ xdbl, const float* __restrict__ dtw,
                                            const float* __restrict__ dtb, bf16* __restrict__ dty){
    int d     = (blockIdx.x & 3)*256 + threadIdx.x;
    int mbase = (blockIdx.x >> 2)*DTMCH;
    float4 w[4];
    #pragma unroll
    for (int q=0;q<4;q++) w[q] = ((const float4*)(dtw + (size_t)d*16))[q];
    float bias = dtb[d];
    __shared__ __align__(16) bf16 xs[DTMCH][16];
    if (threadIdx.x < DTMCH*2){
        int r = threadIdx.x>>1, half = threadIdx.x&1;
        *(uint4*)&xs[r][half*8] = *(const uint4*)(xdbl + (size_t)(mbase+r)*48 + half*8);
    }
    __syncthreads();
    for (int s=0;s<DTMCH;s++){
        bf16x8 x0 = *(const bf16x8*)&xs[s][0];
        bf16x8 x1 = *(const bf16x8*)&xs[s][8];
        float a = bias;
        a=fmaf((float)x0[0],w[0].x,a); a=fmaf((float)x0[1],w[0].y,a);
        a=fmaf((float)x0[2],w[0].z,a); a=fmaf((float)x0[3],w[0].w,a);
        a=fmaf((float)x0[4],w[1].x,a); a=fmaf((float)x0[5],w[1].y,a);
        a=fmaf((float)x0[6],w[1].z,a); a=fmaf((float)x0[7],w[1].w,a);
        a=fmaf((float)x1[0],w[2].x,a); a=fmaf((float)x1[1],w[2].y,a);
        a=fmaf((float)x1[2],w[2].z,a); a=fmaf((float)x1[3],w[2].w,a);
        a=fmaf((float)x1[4],w[3].x,a); a=fmaf((float)x1[5],w[3].y,a);
        a=fmaf((float)x1[6],w[3].z,a); a=fmaf((float)x1[7],w[3].w,a);
        dty[(size_t)(mbase+s)*DINNER + d] = (bf16)softplus_f(a);
    }
}

// ---------------- scan pass 1: per-chunk (P,S), SoA output ----------------
template<int LCHT>
__global__ __launch_bounds__(256) void k_pass1(const bf16* __restrict__ dty, const bf16* __restrict__ xa,
                                               const bf16* __restrict__ xdbl, const float* __restrict__ Alog,
                                               float* __restrict__ Pp, float* __restrict__ Sp, int nch){
    int d = blockIdx.x*256 + threadIdx.x;
    int c = blockIdx.y, b = blockIdx.z;
    int mbase = b*LL + c*LCHT;

    __shared__ __align__(16) bf16 xs[LCHT][16];
    if (threadIdx.x < LCHT*2){
        int row = threadIdx.x>>1, part = threadIdx.x&1;
        *(uint4*)&xs[row][part*8] = *(const uint4*)(xdbl + (size_t)(mbase+row)*48 + 16 + part*8);
    }
    bool st = true;
    float Ald[16];
    {
        const float4* Ap = (const float4*)(Alog + d*16);
        #pragma unroll
        for (int q=0;q<4;q++){
            float4 a4 = Ap[q];
            Ald[q*4+0]=a4.x; Ald[q*4+1]=a4.y; Ald[q*4+2]=a4.z; Ald[q*4+3]=a4.w;
        }
        #pragma unroll
        for (int n=0;n<16;n++) st = st && (fabsf(Ald[n]-LOGT[n]) < 1e-4f);
    }
    __syncthreads();

    float S[16];
    #pragma unroll
    for (int n=0;n<16;n++) S[n]=0.f;
    float sdt = 0.f;

    if (st){
        for (int s=0;s<LCHT;s++){
            int m = mbase + s;
            float dtv = (float)dty[(size_t)m*DINNER + d];
            float xv  = (float)xa [(size_t)m*DINNER + d];
            float dx  = dtv*xv;
            float pw[16];
            powchain(__expf(-dtv), pw);
            bf16x8 b0 = *(const bf16x8*)&xs[s][0];
            bf16x8 b1 = *(const bf16x8*)&xs[s][8];
            #pragma unroll
            for (int n=0;n<8;n++)  S[n]   = fmaf(pw[n],   S[n],   dx*(float)b0[n]);
            #pragma unroll
            for (int n=0;n<8;n++)  S[8+n] = fmaf(pw[8+n], S[8+n], dx*(float)b1[n]);
            sdt += dtv;
        }
    } else {
        float An[16];
        #pragma unroll
        for (int n=0;n<16;n++) An[n] = -__expf(Ald[n]);
        for (int s=0;s<LCHT;s++){
            int m = mbase + s;
            float dtv = (float)dty[(size_t)m*DINNER + d];
            float xv  = (float)xa [(size_t)m*DINNER + d];
            float dx  = dtv*xv;
            bf16x8 b0 = *(const bf16x8*)&xs[s][0];
            bf16x8 b1 = *(const bf16x8*)&xs[s][8];
            #pragma unroll
            for (int n=0;n<8;n++)  S[n]   = fmaf(__expf(dtv*An[n]),   S[n],   dx*(float)b0[n]);
            #pragma unroll
            for (int n=0;n<8;n++)  S[8+n] = fmaf(__expf(dtv*An[8+n]), S[8+n], dx*(float)b1[n]);
            sdt += dtv;
        }
    }
    size_t base = ((size_t)(b*nch + c)*DINNER + d)*16;
    float P[16];
    if (st){
        powchain(__expf(-sdt), P);
    } else {
        float An[16];
        #pragma unroll
        for (int n=0;n<16;n++) An[n] = -__expf(Ald[n]);
        #pragma unroll
        for (int n=0;n<16;n++) P[n] = __expf(An[n]*sdt);
    }
    #pragma unroll
    for (int q=0;q<4;q++){
        *(float4*)&Pp[base+q*4] = make_float4(P[q*4],P[q*4+1],P[q*4+2],P[q*4+3]);
        *(float4*)&Sp[base+q*4] = make_float4(S[q*4],S[q*4+1],S[q*4+2],S[q*4+3]);
    }
}

// ---------------- scan pass 2: cross-chunk prefix; h into P slot ----------------
__global__ __launch_bounds__(256) void k_pass2(float* __restrict__ Pp, float* __restrict__ Sp, int nch){
    int i = blockIdx.x*256 + threadIdx.x;
    int b   = i >> 14;
    int low = i & 16383;
    float h = 0.f;
    for (int c=0;c<nch;c++){
        size_t idx = (size_t)(b*nch + c)*16384 + low;
        float P = Pp[idx], S = Sp[idx];
        Pp[idx] = h;
        h = P*h + S;
    }
}

// ---------------- scan pass 3: replay; y over dt buffer ----------------
template<int LCHT>
__global__ __launch_bounds__(256) void k_pass3(bf16* __restrict__ dty, const bf16* __restrict__ xa,
                                               const bf16* __restrict__ xdbl, const bf16* __restrict__ z,
                                               const float* __restrict__ Alog, const float* __restrict__ Dp,
                                               const float* __restrict__ Pp, int nch){
    int d = blockIdx.x*256 + threadIdx.x;
    int c = blockIdx.y, b = blockIdx.z;
    int mbase = b*LL + c*LCHT;

    __shared__ __align__(16) bf16 xs[LCHT][32];
    if (threadIdx.x < LCHT*4){
        int row = threadIdx.x>>2, part = threadIdx.x&3;
        *(uint4*)&xs[row][part*8] = *(const uint4*)(xdbl + (size_t)(mbase+row)*48 + 16 + part*8);
    }
    bool st = true;
    float Ald[16];
    {
        const float4* Ap = (const float4*)(Alog + d*16);
        #pragma unroll
        for (int q=0;q<4;q++){
            float4 a4 = Ap[q];
            Ald[q*4+0]=a4.x; Ald[q*4+1]=a4.y; Ald[q*4+2]=a4.z; Ald[q*4+3]=a4.w;
        }
        #pragma unroll
        for (int n=0;n<16;n++) st = st && (fabsf(Ald[n]-LOGT[n]) < 1e-4f);
    }
    float h[16];
    size_t hbase = ((size_t)(b*nch + c)*DINNER + d)*16;
    #pragma unroll
    for (int q=0;q<4;q++){
        float4 h4 = *(const float4*)&Pp[hbase+q*4];
        h[q*4]=h4.x; h[q*4+1]=h4.y; h[q*4+2]=h4.z; h[q*4+3]=h4.w;
    }
    float Dd = Dp[d];
    __syncthreads();

    if (st){
        for (int s=0;s<LCHT;s++){
            int m = mbase + s;
            size_t off = (size_t)m*DINNER + d;
            float dtv = (float)dty[off];
            float xv  = (float)xa[off];
            float zv  = (float)z[off];
            float dx  = dtv*xv;
            float pw[16];
            powchain(__expf(-dtv), pw);
            bf16x8 b0 = *(const bf16x8*)&xs[s][0];
            bf16x8 b1 = *(const bf16x8*)&xs[s][8];
            bf16x8 c0 = *(const bf16x8*)&xs[s][16];
            bf16x8 c1 = *(const bf16x8*)&xs[s][24];
            float yv = 0.f;
            #pragma unroll
            for (int n=0;n<8;n++){
                h[n] = fmaf(pw[n], h[n], dx*(float)b0[n]);
                yv   = fmaf(h[n], (float)c0[n], yv);
            }
            #pragma unroll
            for (int n=0;n<8;n++){
                h[8+n] = fmaf(pw[8+n], h[8+n], dx*(float)b1[n]);
                yv     = fmaf(h[8+n], (float)c1[n], yv);
            }
            float g = zv/(1.f+__expf(-zv));
            dty[off] = (bf16)((yv + xv*Dd)*g);
        }
    } else {
        float An[16];
        #pragma unroll
        for (int n=0;n<16;n++) An[n] = -__expf(Ald[n]);
        for (int s=0;s<LCHT;s++){
            int m = mbase + s;
            size_t off = (size_t)m*DINNER + d;
            float dtv = (float)dty[off];
            float xv  = (float)xa[off];
            float zv  = (float)z[off];
            float dx  = dtv*xv;
            bf16x8 b0 = *(const bf16x8*)&xs[s][0];
            bf16x8 b1 = *(const bf16x8*)&xs[s][8];
            bf16x8 c0 = *(const bf16x8*)&xs[s][16];
            bf16x8 c1 = *(const bf16x8*)&xs[s][24];
            float yv = 0.f;
            #pragma unroll
            for (int n=0;n<8;n++){
                h[n] = fmaf(__expf(dtv*An[n]), h[n], dx*(float)b0[n]);
                yv   = fmaf(h[n], (float)c0[n], yv);
            }
            #pragma unroll
            for (int n=0;n<8;n++){
                h[8+n] = fmaf(__expf(dtv*An[8+n]), h[8+n], dx*(float)b1[n]);
                yv     = fmaf(h[8+n], (float)c1[n], yv);
            }
            float g = zv/(1.f+__expf(-zv));
            dty[off] = (bf16)((yv + xv*Dd)*g);
        }
    }
}

extern "C" void kernel_launch(void* const* d_in, const int* in_sizes, int n_in,
                              void* d_out, int out_size, void* d_ws, size_t ws_size,
                              hipStream_t stream) {
    const float* x     = (const float*)d_in[0];
    const float* normw = (const float*)d_in[1];
    const float* w_in  = (const float*)d_in[2];
    const float* convw = (const float*)d_in[3];
    const float* convb = (const float*)d_in[4];
    const float* w_xp  = (const float*)d_in[5];
    const float* dtw   = (const float*)d_in[6];
    const float* dtb   = (const float*)d_in[7];
    const float* Alog  = (const float*)d_in[8];
    const float* Dp    = (const float*)d_in[9];
    const float* w_out = (const float*)d_in[10];

    const size_t WB    = ((size_t)2048*256 + 48*1024 + 256*1024)*2;
    const size_t WB_AL = (WB + 255) & ~(size_t)255;
    auto need = [WB_AL](int nb, int nch)->size_t{
        size_t rows = (size_t)nb*LL;
        size_t big  = rows*DINNER*2;
        size_t xd   = ((rows*48*2) + 255) & ~(size_t)255;
        size_t ps   = (size_t)nb*nch*DINNER*16*8;
        return WB_AL + 3*big + xd + ps;
    };
    const int cands[8][2] = {{8,128},{8,64},{4,128},{4,64},{2,128},{2,64},{1,128},{1,64}};
    int NB = 0, NCHv = 0;
    for (int k=0;k<8;k++) if (need(cands[k][0], cands[k][1]) <= ws_size){ NB=cands[k][0]; NCHv=cands[k][1]; break; }
    if (!NB){
        k_wsfail<<<(out_size+255)/256, 256, 0, stream>>>((float*)d_out, out_size);
        return;
    }
    const int LCHv = LL/NCHv;

    char* ws = (char*)d_ws;
    bf16* win_b  = (bf16*)ws;
    bf16* wxp_b  = (bf16*)(ws + (size_t)2048*256*2);
    bf16* wout_b = (bf16*)(ws + (size_t)2048*256*2 + (size_t)48*1024*2);

    size_t rows  = (size_t)NB*LL;
    size_t big   = rows*DINNER*2;
    size_t xd_al = ((rows*48*2) + 255) & ~(size_t)255;
    char*  ar    = ws + WB_AL;
    bf16*  xcy   = (bf16*)ar;            // xc -> dt -> y
    bf16*  zb    = (bf16*)(ar + big);
    bf16*  xab   = (bf16*)(ar + 2*big);
    bf16*  xdb   = (bf16*)(ar + 3*big);
    float* Pp    = (float*)(ar + 3*big + xd_al);
    float* Sp    = Pp + (size_t)NB*NCHv*DINNER*16;
    bf16*  hb    = (bf16*)Pp;            // overlaps PS (disjoint lifetimes)

    k_cast3<<<(2048*256 + 48*1024 + 256*1024)/256, 256, 0, stream>>>(
        w_in, w_xp, w_out, win_b, wxp_b, wout_b, 2048*256, 48*1024, 256*1024);

    for (int b0=0; b0<BB; b0+=NB){
        const float* xb = x + (size_t)b0*LL*DMODEL;
        float*       ob = (float*)d_out + (size_t)b0*LL*DMODEL;
        k_rms<<<(int)rows, 256, 0, stream>>>(xb, normw, hb);
        k_gemm<1,false><<<dim3((int)rows/128, 16), 256, 0, stream>>>(
            hb, win_b, xcy, zb, nullptr, nullptr, (int)rows, 2048, 256);
        k_conv<<<(int)(rows*DINNER/8/256), 256, 0, stream>>>(xcy, convw, convb, xab);
        k_gemm<0,true><<<dim3((int)rows/128, 1), 256, 0, stream>>>(
            xab, wxp_b, xdb, nullptr, nullptr, nullptr, (int)rows, 48, 1024);
        k_dt<<<(int)(rows/DTMCH)*4, 256, 0, stream>>>(xdb, dtw, dtb, xcy);
        if (LCHv == 64){
            k_pass1<64><<<dim3(4, NCHv, NB), 256, 0, stream>>>(xcy, xab, xdb, Alog, Pp, Sp, NCHv);
            k_pass2<<<NB*64, 256, 0, stream>>>(Pp, Sp, NCHv);
            k_pass3<64><<<dim3(4, NCHv, NB), 256, 0, stream>>>(xcy, xab, xdb, zb, Alog, Dp, Pp, NCHv);
        } else {
            k_pass1<32><<<dim3(4, NCHv, NB), 256, 0, stream>>>(xcy, xab, xdb, Alog, Pp, Sp, NCHv);
            k_pass2<<<NB*64, 256, 0, stream>>>(Pp, Sp, NCHv);
            k_pass3<32><<<dim3(4, NCHv, NB), 256, 0, stream>>>(xcy, xab, xdb, zb, Alog, Dp, Pp, NCHv);
        }
        k_gemm<2,false><<<dim3((int)rows/128, 2), 256, 0, stream>>>(
            xcy, wout_b, nullptr, nullptr, ob, xb, (int)rows, 256, 1024);
    }
}

// Round 6
// 559.564 us; speedup vs baseline: 1.7041x; 1.1596x over previous
//
#include <hip/hip_runtime.h>
#include <hip/hip_bf16.h>
#include <cstdint>
#include <cstddef>

typedef __bf16 bf16;
typedef __attribute__((ext_vector_type(8))) __bf16 bf16x8;
typedef __attribute__((ext_vector_type(4))) float f32x4;

#define BB 8
#define LL 4096
#define DMODEL 256
#define DINNER 1024
#define MT (BB*LL)
#define CT 8                 // conv timesteps per thread

__constant__ float LOGT[16] = {
    0.0f, 0.6931471806f, 1.0986122887f, 1.3862943611f,
    1.6094379124f, 1.7917594692f, 1.9459101091f, 2.0794415417f,
    2.1972245773f, 2.3025850930f, 2.3978952728f, 2.4849066498f,
    2.5649493575f, 2.6390573296f, 2.7080502011f, 2.7725887222f};

// ---------------- sentinel when ws is too small ----------------
__global__ __launch_bounds__(256) void k_wsfail(float* out, int n){
    int i = blockIdx.x*256 + threadIdx.x;
    if (i < n) out[i] = 1e9f;
}

// ---------------- cast three fp32 weight arrays to bf16 ----------------
__global__ __launch_bounds__(256) void k_cast3(const float* __restrict__ s1, const float* __restrict__ s2,
                                               const float* __restrict__ s3,
                                               bf16* __restrict__ o1, bf16* __restrict__ o2, bf16* __restrict__ o3,
                                               int n1, int n2, int n3){
    int i = blockIdx.x*256 + threadIdx.x;
    if (i < n1) o1[i] = (bf16)s1[i];
    else if (i < n1+n2) o2[i-n1] = (bf16)s2[i-n1];
    else if (i < n1+n2+n3) o3[i-n1-n2] = (bf16)s3[i-n1-n2];
}

// ---------------- RMSNorm ----------------
__global__ __launch_bounds__(256) void k_rms(const float* __restrict__ x, const float* __restrict__ w,
                                             bf16* __restrict__ h){
    int m = blockIdx.x, t = threadIdx.x;
    float v = x[(size_t)m*DMODEL + t];
    float s = v*v;
    #pragma unroll
    for (int o=1;o<64;o<<=1) s += __shfl_xor(s, o, 64);
    __shared__ float ps[4];
    if ((t&63)==0) ps[t>>6] = s;
    __syncthreads();
    float tot = ps[0]+ps[1]+ps[2]+ps[3];
    float inv = rsqrtf(tot*(1.0f/DMODEL) + 1e-5f);
    h[(size_t)m*DMODEL + t] = (bf16)(v*inv*w[t]);
}

// ---------------- bf16 MFMA GEMM ----------------
template<int MODE, bool NMASK>
__global__ __launch_bounds__(256) void k_gemm(const bf16* __restrict__ A, const bf16* __restrict__ Bw,
                                              bf16* __restrict__ C1, bf16* __restrict__ C2,
                                              float* __restrict__ Cf, const float* __restrict__ res,
                                              int M, int N, int K){
    __shared__ __align__(16) bf16 As[128][40];
    __shared__ __align__(16) bf16 Bs[128][40];
    const int tid  = threadIdx.x;
    const int m0   = blockIdx.x*128, n0 = blockIdx.y*128;
    const int wave = tid>>6, lane = tid&63;
    const int wr   = wave>>1, wc = wave&1;
    const int fr   = lane&15, kg = lane>>4;
    const int srow = tid>>1, shalf = tid&1;

    f32x4 acc[4][4] = {};

    for (int kt=0; kt<K; kt+=32){
        {
            const bf16* g = A + (size_t)(m0+srow)*K + kt + shalf*16;
            uint4 v0 = *(const uint4*)g;
            uint4 v1 = *(const uint4*)(g+8);
            *(uint4*)&As[srow][shalf*16]   = v0;
            *(uint4*)&As[srow][shalf*16+8] = v1;
        }
        {
            uint4 v0 = make_uint4(0,0,0,0), v1 = make_uint4(0,0,0,0);
            int nr = n0 + srow;
            if (!NMASK || nr < N){
                const bf16* g = Bw + (size_t)nr*K + kt + shalf*16;
                v0 = *(const uint4*)g; v1 = *(const uint4*)(g+8);
            }
            *(uint4*)&Bs[srow][shalf*16]   = v0;
            *(uint4*)&Bs[srow][shalf*16+8] = v1;
        }
        __syncthreads();
        bf16x8 af[4], bfv[4];
        #pragma unroll
        for (int i=0;i<4;i++) af[i]  = *(const bf16x8*)&As[wr*64 + i*16 + fr][kg*8];
        #pragma unroll
        for (int j=0;j<4;j++) bfv[j] = *(const bf16x8*)&Bs[wc*64 + j*16 + fr][kg*8];
        #pragma unroll
        for (int i=0;i<4;i++)
            #pragma unroll
            for (int j=0;j<4;j++)
                acc[i][j] = __builtin_amdgcn_mfma_f32_16x16x32_bf16(af[i], bfv[j], acc[i][j], 0,0,0);
        __syncthreads();
    }
    #pragma unroll
    for (int i=0;i<4;i++)
        #pragma unroll
        for (int j=0;j<4;j++)
            #pragma unroll
            for (int r=0;r<4;r++){
                int row = m0 + wr*64 + i*16 + kg*4 + r;
                int col = n0 + wc*64 + j*16 + fr;
                float v = acc[i][j][r];
                if (MODE==0){
                    if (!NMASK || col < N) C1[(size_t)row*N + col] = (bf16)v;
                } else if (MODE==1){
                    bf16* dst = (col < 1024) ? C1 : C2;
                    dst[(size_t)row*1024 + (col & 1023)] = (bf16)v;
                } else {
                    size_t o = (size_t)row*N + col;
                    Cf[o] = v + res[o];
                }
            }
}

// ---------------- depthwise causal conv + SiLU, sliding window, CT steps/thread ----------------
__global__ __launch_bounds__(256) void k_conv(const bf16* __restrict__ xc, const float* __restrict__ cw,
                                              const float* __restrict__ cb, bf16* __restrict__ xa){
    int i  = blockIdx.x*256 + threadIdx.x;     // over (rows/CT)*128
    int dv = i & 127;
    int mc = i >> 7;
    int d0 = dv*8;
    int m0 = mc*CT;
    int t0 = m0 & (LL-1);

    float4 w4[8];
    #pragma unroll
    for (int q=0;q<8;q++) w4[q] = *(const float4*)(cw + (size_t)(d0+q)*4);
    float bias[8];
    {
        float4 b0 = *(const float4*)(cb + d0);
        float4 b1 = *(const float4*)(cb + d0 + 4);
        bias[0]=b0.x; bias[1]=b0.y; bias[2]=b0.z; bias[3]=b0.w;
        bias[4]=b1.x; bias[5]=b1.y; bias[6]=b1.z; bias[7]=b1.w;
    }
    const bf16* base = xc + (size_t)m0*DINNER + d0;
    bf16* outp       = xa + (size_t)m0*DINNER + d0;
    bf16x8 p3 = {}, p2 = {}, p1 = {};          // rows m-3, m-2, m-1
    if (t0 > 0){                               // t0 is a multiple of CT>=4, so all 3 valid
        p3 = *(const bf16x8*)(base - 3*DINNER);
        p2 = *(const bf16x8*)(base - 2*DINNER);
        p1 = *(const bf16x8*)(base - 1*DINNER);
    }
    #pragma unroll
    for (int s=0;s<CT;s++){
        bf16x8 cur = *(const bf16x8*)(base + (size_t)s*DINNER);
        bf16x8 o;
        #pragma unroll
        for (int q=0;q<8;q++){
            float a = bias[q];
            a = fmaf((float)p3[q],  w4[q].x, a);
            a = fmaf((float)p2[q],  w4[q].y, a);
            a = fmaf((float)p1[q],  w4[q].z, a);
            a = fmaf((float)cur[q], w4[q].w, a);
            o[q] = (bf16)(a/(1.f+__expf(-a)));
        }
        *(bf16x8*)(outp + (size_t)s*DINNER) = o;
        p3 = p2; p2 = p1; p1 = cur;
    }
}

__device__ __forceinline__ float softplus_f(float a){
    return fmaxf(a, 0.f) + __logf(1.f + __expf(-fabsf(a)));
}

// pw[n] = p^(n+1), depth-4 multiply tree
__device__ __forceinline__ void powchain(float p, float* pw){
    pw[0]=p;
    pw[1]=pw[0]*pw[0];  pw[2]=pw[1]*pw[0];  pw[3]=pw[1]*pw[1];
    pw[4]=pw[1]*pw[2];  pw[5]=pw[2]*pw[2];  pw[6]=pw[2]*pw[3];  pw[7]=pw[3]*pw[3];
    pw[8]=pw[3]*pw[4];  pw[9]=pw[4]*pw[4];  pw[10]=pw[4]*pw[5]; pw[11]=pw[5]*pw[5];
    pw[12]=pw[5]*pw[6]; pw[13]=pw[6]*pw[6]; pw[14]=pw[6]*pw[7]; pw[15]=pw[7]*pw[7];
}

// dt-dot from LDS row + register weights
__device__ __forceinline__ float dt_dot(const bf16* xr, const float4* w, float bias){
    bf16x8 x0 = *(const bf16x8*)&xr[0];
    bf16x8 x1 = *(const bf16x8*)&xr[8];
    float a = bias;
    a=fmaf((float)x0[0],w[0].x,a); a=fmaf((float)x0[1],w[0].y,a);
    a=fmaf((float)x0[2],w[0].z,a); a=fmaf((float)x0[3],w[0].w,a);
    a=fmaf((float)x0[4],w[1].x,a); a=fmaf((float)x0[5],w[1].y,a);
    a=fmaf((float)x0[6],w[1].z,a); a=fmaf((float)x0[7],w[1].w,a);
    a=fmaf((float)x1[0],w[2].x,a); a=fmaf((float)x1[1],w[2].y,a);
    a=fmaf((float)x1[2],w[2].z,a); a=fmaf((float)x1[3],w[2].w,a);
    a=fmaf((float)x1[4],w[3].x,a); a=fmaf((float)x1[5],w[3].y,a);
    a=fmaf((float)x1[6],w[3].z,a); a=fmaf((float)x1[7],w[3].w,a);
    return softplus_f(a);
}

// ---------------- scan pass 1: per-chunk (P,S), dt fused, SoA output ----------------
template<int LCHT>
__global__ __launch_bounds__(256) void k_pass1(const bf16* __restrict__ xa, const bf16* __restrict__ xdbl,
                                               const float* __restrict__ Alog, const float* __restrict__ dtw,
                                               const float* __restrict__ dtb,
                                               float* __restrict__ Pp, float* __restrict__ Sp, int nch){
    int d = blockIdx.x*256 + threadIdx.x;
    int c = blockIdx.y, b = blockIdx.z;
    int mbase = b*LL + c*LCHT;

    __shared__ __align__(16) bf16 xs[LCHT][32];      // cols 0-15: dt-rank, 16-31: B
    for (int idx=threadIdx.x; idx<LCHT*4; idx+=256){
        int row = idx>>2, part = idx&3;
        *(uint4*)&xs[row][part*8] = *(const uint4*)(xdbl + (size_t)(mbase+row)*48 + part*8);
    }
    bool st = true;
    float Ald[16];
    {
        const float4* Ap = (const float4*)(Alog + d*16);
        #pragma unroll
        for (int q=0;q<4;q++){
            float4 a4 = Ap[q];
            Ald[q*4+0]=a4.x; Ald[q*4+1]=a4.y; Ald[q*4+2]=a4.z; Ald[q*4+3]=a4.w;
        }
        #pragma unroll
        for (int n=0;n<16;n++) st = st && (fabsf(Ald[n]-LOGT[n]) < 1e-4f);
    }
    float4 w[4];
    #pragma unroll
    for (int q=0;q<4;q++) w[q] = ((const float4*)(dtw + (size_t)d*16))[q];
    float bias = dtb[d];
    __syncthreads();

    float S[16];
    #pragma unroll
    for (int n=0;n<16;n++) S[n]=0.f;
    float sdt = 0.f;

    if (st){
        for (int s=0;s<LCHT;s++){
            int m = mbase + s;
            float dtv = dt_dot(&xs[s][0], w, bias);
            float xv  = (float)xa[(size_t)m*DINNER + d];
            float dx  = dtv*xv;
            float pw[16];
            powchain(__expf(-dtv), pw);
            bf16x8 b0 = *(const bf16x8*)&xs[s][16];
            bf16x8 b1 = *(const bf16x8*)&xs[s][24];
            #pragma unroll
            for (int n=0;n<8;n++)  S[n]   = fmaf(pw[n],   S[n],   dx*(float)b0[n]);
            #pragma unroll
            for (int n=0;n<8;n++)  S[8+n] = fmaf(pw[8+n], S[8+n], dx*(float)b1[n]);
            sdt += dtv;
        }
    } else {
        float An[16];
        #pragma unroll
        for (int n=0;n<16;n++) An[n] = -__expf(Ald[n]);
        for (int s=0;s<LCHT;s++){
            int m = mbase + s;
            float dtv = dt_dot(&xs[s][0], w, bias);
            float xv  = (float)xa[(size_t)m*DINNER + d];
            float dx  = dtv*xv;
            bf16x8 b0 = *(const bf16x8*)&xs[s][16];
            bf16x8 b1 = *(const bf16x8*)&xs[s][24];
            #pragma unroll
            for (int n=0;n<8;n++)  S[n]   = fmaf(__expf(dtv*An[n]),   S[n],   dx*(float)b0[n]);
            #pragma unroll
            for (int n=0;n<8;n++)  S[8+n] = fmaf(__expf(dtv*An[8+n]), S[8+n], dx*(float)b1[n]);
            sdt += dtv;
        }
    }
    size_t base = ((size_t)(b*nch + c)*DINNER + d)*16;
    float P[16];
    if (st){
        powchain(__expf(-sdt), P);
    } else {
        float An[16];
        #pragma unroll
        for (int n=0;n<16;n++) An[n] = -__expf(Ald[n]);
        #pragma unroll
        for (int n=0;n<16;n++) P[n] = __expf(An[n]*sdt);
    }
    #pragma unroll
    for (int q=0;q<4;q++){
        *(float4*)&Pp[base+q*4] = make_float4(P[q*4],P[q*4+1],P[q*4+2],P[q*4+3]);
        *(float4*)&Sp[base+q*4] = make_float4(S[q*4],S[q*4+1],S[q*4+2],S[q*4+3]);
    }
}

// ---------------- scan pass 2: cross-chunk prefix; h into P slot ----------------
__global__ __launch_bounds__(256) void k_pass2(float* __restrict__ Pp, float* __restrict__ Sp, int nch){
    int i = blockIdx.x*256 + threadIdx.x;
    int b   = i >> 14;
    int low = i & 16383;
    float h = 0.f;
    for (int c=0;c<nch;c++){
        size_t idx = (size_t)(b*nch + c)*16384 + low;
        float P = Pp[idx], S = Sp[idx];
        Pp[idx] = h;
        h = P*h + S;
    }
}

// ---------------- scan pass 3: replay, dt fused; y + skip + SiLU(z) gate ----------------
template<int LCHT>
__global__ __launch_bounds__(256) void k_pass3(bf16* __restrict__ y, const bf16* __restrict__ xa,
                                               const bf16* __restrict__ xdbl, const bf16* __restrict__ z,
                                               const float* __restrict__ Alog, const float* __restrict__ dtw,
                                               const float* __restrict__ dtb, const float* __restrict__ Dp,
                                               const float* __restrict__ Pp, int nch){
    int d = blockIdx.x*256 + threadIdx.x;
    int c = blockIdx.y, b = blockIdx.z;
    int mbase = b*LL + c*LCHT;

    __shared__ __align__(16) bf16 xs[LCHT][48];      // 0-15 dt-rank, 16-31 B, 32-47 C
    for (int idx=threadIdx.x; idx<LCHT*6; idx+=256){
        int row = idx/6, part = idx - row*6;
        *(uint4*)&xs[row][part*8] = *(const uint4*)(xdbl + (size_t)(mbase+row)*48 + part*8);
    }
    bool st = true;
    float Ald[16];
    {
        const float4* Ap = (const float4*)(Alog + d*16);
        #pragma unroll
        for (int q=0;q<4;q++){
            float4 a4 = Ap[q];
            Ald[q*4+0]=a4.x; Ald[q*4+1]=a4.y; Ald[q*4+2]=a4.z; Ald[q*4+3]=a4.w;
        }
        #pragma unroll
        for (int n=0;n<16;n++) st = st && (fabsf(Ald[n]-LOGT[n]) < 1e-4f);
    }
    float4 w[4];
    #pragma unroll
    for (int q=0;q<4;q++) w[q] = ((const float4*)(dtw + (size_t)d*16))[q];
    float bias = dtb[d];
    float h[16];
    size_t hbase = ((size_t)(b*nch + c)*DINNER + d)*16;
    #pragma unroll
    for (int q=0;q<4;q++){
        float4 h4 = *(const float4*)&Pp[hbase+q*4];
        h[q*4]=h4.x; h[q*4+1]=h4.y; h[q*4+2]=h4.z; h[q*4+3]=h4.w;
    }
    float Dd = Dp[d];
    __syncthreads();

    if (st){
        for (int s=0;s<LCHT;s++){
            int m = mbase + s;
            size_t off = (size_t)m*DINNER + d;
            float dtv = dt_dot(&xs[s][0], w, bias);
            float xv  = (float)xa[off];
            float zv  = (float)z[off];
            float dx  = dtv*xv;
            float pw[16];
            powchain(__expf(-dtv), pw);
            bf16x8 b0 = *(const bf16x8*)&xs[s][16];
            bf16x8 b1 = *(const bf16x8*)&xs[s][24];
            bf16x8 c0 = *(const bf16x8*)&xs[s][32];
            bf16x8 c1 = *(const bf16x8*)&xs[s][40];
            float yv = 0.f;
            #pragma unroll
            for (int n=0;n<8;n++){
                h[n] = fmaf(pw[n], h[n], dx*(float)b0[n]);
                yv   = fmaf(h[n], (float)c0[n], yv);
            }
            #pragma unroll
            for (int n=0;n<8;n++){
                h[8+n] = fmaf(pw[8+n], h[8+n], dx*(float)b1[n]);
                yv     = fmaf(h[8+n], (float)c1[n], yv);
            }
            float g = zv/(1.f+__expf(-zv));
            y[off] = (bf16)((yv + xv*Dd)*g);
        }
    } else {
        float An[16];
        #pragma unroll
        for (int n=0;n<16;n++) An[n] = -__expf(Ald[n]);
        for (int s=0;s<LCHT;s++){
            int m = mbase + s;
            size_t off = (size_t)m*DINNER + d;
            float dtv = dt_dot(&xs[s][0], w, bias);
            float xv  = (float)xa[off];
            float zv  = (float)z[off];
            float dx  = dtv*xv;
            bf16x8 b0 = *(const bf16x8*)&xs[s][16];
            bf16x8 b1 = *(const bf16x8*)&xs[s][24];
            bf16x8 c0 = *(const bf16x8*)&xs[s][32];
            bf16x8 c1 = *(const bf16x8*)&xs[s][40];
            float yv = 0.f;
            #pragma unroll
            for (int n=0;n<8;n++){
                h[n] = fmaf(__expf(dtv*An[n]), h[n], dx*(float)b0[n]);
                yv   = fmaf(h[n], (float)c0[n], yv);
            }
            #pragma unroll
            for (int n=0;n<8;n++){
                h[8+n] = fmaf(__expf(dtv*An[8+n]), h[8+n], dx*(float)b1[n]);
                yv     = fmaf(h[8+n], (float)c1[n], yv);
            }
            float g = zv/(1.f+__expf(-zv));
            y[off] = (bf16)((yv + xv*Dd)*g);
        }
    }
}

extern "C" void kernel_launch(void* const* d_in, const int* in_sizes, int n_in,
                              void* d_out, int out_size, void* d_ws, size_t ws_size,
                              hipStream_t stream) {
    const float* x     = (const float*)d_in[0];
    const float* normw = (const float*)d_in[1];
    const float* w_in  = (const float*)d_in[2];
    const float* convw = (const float*)d_in[3];
    const float* convb = (const float*)d_in[4];
    const float* w_xp  = (const float*)d_in[5];
    const float* dtw   = (const float*)d_in[6];
    const float* dtb   = (const float*)d_in[7];
    const float* Alog  = (const float*)d_in[8];
    const float* Dp    = (const float*)d_in[9];
    const float* w_out = (const float*)d_in[10];

    const size_t WB    = ((size_t)2048*256 + 48*1024 + 256*1024)*2;
    const size_t WB_AL = (WB + 255) & ~(size_t)255;
    auto need = [WB_AL](int nb, int nch)->size_t{
        size_t rows = (size_t)nb*LL;
        size_t big  = rows*DINNER*2;
        size_t xd   = ((rows*48*2) + 255) & ~(size_t)255;
        size_t ps   = (size_t)nb*nch*DINNER*16*8;
        return WB_AL + 3*big + xd + ps;
    };
    const int cands[8][2] = {{8,128},{8,64},{4,128},{4,64},{2,128},{2,64},{1,128},{1,64}};
    int NB = 0, NCHv = 0;
    for (int k=0;k<8;k++) if (need(cands[k][0], cands[k][1]) <= ws_size){ NB=cands[k][0]; NCHv=cands[k][1]; break; }
    if (!NB){
        k_wsfail<<<(out_size+255)/256, 256, 0, stream>>>((float*)d_out, out_size);
        return;
    }
    const int LCHv = LL/NCHv;

    char* ws = (char*)d_ws;
    bf16* win_b  = (bf16*)ws;
    bf16* wxp_b  = (bf16*)(ws + (size_t)2048*256*2);
    bf16* wout_b = (bf16*)(ws + (size_t)2048*256*2 + (size_t)48*1024*2);

    size_t rows  = (size_t)NB*LL;
    size_t big   = rows*DINNER*2;
    size_t xd_al = ((rows*48*2) + 255) & ~(size_t)255;
    char*  ar    = ws + WB_AL;
    bf16*  xcy   = (bf16*)ar;            // xc -> y
    bf16*  zb    = (bf16*)(ar + big);
    bf16*  xab   = (bf16*)(ar + 2*big);
    bf16*  xdb   = (bf16*)(ar + 3*big);
    float* Pp    = (float*)(ar + 3*big + xd_al);
    float* Sp    = Pp + (size_t)NB*NCHv*DINNER*16;
    bf16*  hb    = (bf16*)Pp;            // overlaps PS (disjoint lifetimes)

    k_cast3<<<(2048*256 + 48*1024 + 256*1024)/256, 256, 0, stream>>>(
        w_in, w_xp, w_out, win_b, wxp_b, wout_b, 2048*256, 48*1024, 256*1024);

    for (int b0=0; b0<BB; b0+=NB){
        const float* xb = x + (size_t)b0*LL*DMODEL;
        float*       ob = (float*)d_out + (size_t)b0*LL*DMODEL;
        k_rms<<<(int)rows, 256, 0, stream>>>(xb, normw, hb);
        k_gemm<1,false><<<dim3((int)rows/128, 16), 256, 0, stream>>>(
            hb, win_b, xcy, zb, nullptr, nullptr, (int)rows, 2048, 256);
        k_conv<<<(int)(rows/(CT*2)), 256, 0, stream>>>(xcy, convw, convb, xab);
        k_gemm<0,true><<<dim3((int)rows/128, 1), 256, 0, stream>>>(
            xab, wxp_b, xdb, nullptr, nullptr, nullptr, (int)rows, 48, 1024);
        if (LCHv == 64){
            k_pass1<64><<<dim3(4, NCHv, NB), 256, 0, stream>>>(xab, xdb, Alog, dtw, dtb, Pp, Sp, NCHv);
            k_pass2<<<NB*64, 256, 0, stream>>>(Pp, Sp, NCHv);
            k_pass3<64><<<dim3(4, NCHv, NB), 256, 0, stream>>>(xcy, xab, xdb, zb, Alog, dtw, dtb, Dp, Pp, NCHv);
        } else {
            k_pass1<32><<<dim3(4, NCHv, NB), 256, 0, stream>>>(xab, xdb, Alog, dtw, dtb, Pp, Sp, NCHv);
            k_pass2<<<NB*64, 256, 0, stream>>>(Pp, Sp, NCHv);
            k_pass3<32><<<dim3(4, NCHv, NB), 256, 0, stream>>>(xcy, xab, xdb, zb, Alog, dtw, dtb, Dp, Pp, NCHv);
        }
        k_gemm<2,false><<<dim3((int)rows/128, 2), 256, 0, stream>>>(
            xcy, wout_b, nullptr, nullptr, ob, xb, (int)rows, 256, 1024);
    }
}

// Round 7
// 531.087 us; speedup vs baseline: 1.7955x; 1.0536x over previous
//
#include <hip/hip_runtime.h>
#include <hip/hip_bf16.h>
#include <cstdint>
#include <cstddef>

typedef __bf16 bf16;
typedef __attribute__((ext_vector_type(8))) __bf16 bf16x8;
typedef __attribute__((ext_vector_type(4))) float f32x4;

#define BB 8
#define LL 4096
#define DMODEL 256
#define DINNER 1024
#define MT (BB*LL)
#define CT 8                 // conv timesteps per thread
#define DTMCH 64             // k_dt m-chunk

__constant__ float LOGT[16] = {
    0.0f, 0.6931471806f, 1.0986122887f, 1.3862943611f,
    1.6094379124f, 1.7917594692f, 1.9459101091f, 2.0794415417f,
    2.1972245773f, 2.3025850930f, 2.3978952728f, 2.4849066498f,
    2.5649493575f, 2.6390573296f, 2.7080502011f, 2.7725887222f};

// ---------------- sentinel when ws is too small ----------------
__global__ __launch_bounds__(256) void k_wsfail(float* out, int n){
    int i = blockIdx.x*256 + threadIdx.x;
    if (i < n) out[i] = 1e9f;
}

// ---------------- cast three fp32 weight arrays to bf16 ----------------
__global__ __launch_bounds__(256) void k_cast3(const float* __restrict__ s1, const float* __restrict__ s2,
                                               const float* __restrict__ s3,
                                               bf16* __restrict__ o1, bf16* __restrict__ o2, bf16* __restrict__ o3,
                                               int n1, int n2, int n3){
    int i = blockIdx.x*256 + threadIdx.x;
    if (i < n1) o1[i] = (bf16)s1[i];
    else if (i < n1+n2) o2[i-n1] = (bf16)s2[i-n1];
    else if (i < n1+n2+n3) o3[i-n1-n2] = (bf16)s3[i-n1-n2];
}

// ---------------- RMSNorm ----------------
__global__ __launch_bounds__(256) void k_rms(const float* __restrict__ x, const float* __restrict__ w,
                                             bf16* __restrict__ h){
    int m = blockIdx.x, t = threadIdx.x;
    float v = x[(size_t)m*DMODEL + t];
    float s = v*v;
    #pragma unroll
    for (int o=1;o<64;o<<=1) s += __shfl_xor(s, o, 64);
    __shared__ float ps[4];
    if ((t&63)==0) ps[t>>6] = s;
    __syncthreads();
    float tot = ps[0]+ps[1]+ps[2]+ps[3];
    float inv = rsqrtf(tot*(1.0f/DMODEL) + 1e-5f);
    h[(size_t)m*DMODEL + t] = (bf16)(v*inv*w[t]);
}

// ---------------- bf16 MFMA GEMM ----------------
template<int MODE, bool NMASK>
__global__ __launch_bounds__(256) void k_gemm(const bf16* __restrict__ A, const bf16* __restrict__ Bw,
                                              bf16* __restrict__ C1, bf16* __restrict__ C2,
                                              float* __restrict__ Cf, const float* __restrict__ res,
                                              int M, int N, int K){
    __shared__ __align__(16) bf16 As[128][40];
    __shared__ __align__(16) bf16 Bs[128][40];
    const int tid  = threadIdx.x;
    const int m0   = blockIdx.x*128, n0 = blockIdx.y*128;
    const int wave = tid>>6, lane = tid&63;
    const int wr   = wave>>1, wc = wave&1;
    const int fr   = lane&15, kg = lane>>4;
    const int srow = tid>>1, shalf = tid&1;

    f32x4 acc[4][4] = {};

    for (int kt=0; kt<K; kt+=32){
        {
            const bf16* g = A + (size_t)(m0+srow)*K + kt + shalf*16;
            uint4 v0 = *(const uint4*)g;
            uint4 v1 = *(const uint4*)(g+8);
            *(uint4*)&As[srow][shalf*16]   = v0;
            *(uint4*)&As[srow][shalf*16+8] = v1;
        }
        {
            uint4 v0 = make_uint4(0,0,0,0), v1 = make_uint4(0,0,0,0);
            int nr = n0 + srow;
            if (!NMASK || nr < N){
                const bf16* g = Bw + (size_t)nr*K + kt + shalf*16;
                v0 = *(const uint4*)g; v1 = *(const uint4*)(g+8);
            }
            *(uint4*)&Bs[srow][shalf*16]   = v0;
            *(uint4*)&Bs[srow][shalf*16+8] = v1;
        }
        __syncthreads();
        bf16x8 af[4], bfv[4];
        #pragma unroll
        for (int i=0;i<4;i++) af[i]  = *(const bf16x8*)&As[wr*64 + i*16 + fr][kg*8];
        #pragma unroll
        for (int j=0;j<4;j++) bfv[j] = *(const bf16x8*)&Bs[wc*64 + j*16 + fr][kg*8];
        #pragma unroll
        for (int i=0;i<4;i++)
            #pragma unroll
            for (int j=0;j<4;j++)
                acc[i][j] = __builtin_amdgcn_mfma_f32_16x16x32_bf16(af[i], bfv[j], acc[i][j], 0,0,0);
        __syncthreads();
    }
    #pragma unroll
    for (int i=0;i<4;i++)
        #pragma unroll
        for (int j=0;j<4;j++)
            #pragma unroll
            for (int r=0;r<4;r++){
                int row = m0 + wr*64 + i*16 + kg*4 + r;
                int col = n0 + wc*64 + j*16 + fr;
                float v = acc[i][j][r];
                if (MODE==0){
                    if (!NMASK || col < N) C1[(size_t)row*N + col] = (bf16)v;
                } else if (MODE==1){
                    bf16* dst = (col < 1024) ? C1 : C2;
                    dst[(size_t)row*1024 + (col & 1023)] = (bf16)v;
                } else {
                    size_t o = (size_t)row*N + col;
                    Cf[o] = v + res[o];
                }
            }
}

// ---------------- depthwise causal conv + SiLU, sliding window ----------------
__global__ __launch_bounds__(256) void k_conv(const bf16* __restrict__ xc, const float* __restrict__ cw,
                                              const float* __restrict__ cb, bf16* __restrict__ xa){
    int i  = blockIdx.x*256 + threadIdx.x;
    int dv = i & 127;
    int mc = i >> 7;
    int d0 = dv*8;
    int m0 = mc*CT;
    int t0 = m0 & (LL-1);

    float4 w4[8];
    #pragma unroll
    for (int q=0;q<8;q++) w4[q] = *(const float4*)(cw + (size_t)(d0+q)*4);
    float bias[8];
    {
        float4 b0 = *(const float4*)(cb + d0);
        float4 b1 = *(const float4*)(cb + d0 + 4);
        bias[0]=b0.x; bias[1]=b0.y; bias[2]=b0.z; bias[3]=b0.w;
        bias[4]=b1.x; bias[5]=b1.y; bias[6]=b1.z; bias[7]=b1.w;
    }
    const bf16* base = xc + (size_t)m0*DINNER + d0;
    bf16* outp       = xa + (size_t)m0*DINNER + d0;
    bf16x8 p3 = {}, p2 = {}, p1 = {};
    if (t0 > 0){
        p3 = *(const bf16x8*)(base - 3*DINNER);
        p2 = *(const bf16x8*)(base - 2*DINNER);
        p1 = *(const bf16x8*)(base - 1*DINNER);
    }
    #pragma unroll
    for (int s=0;s<CT;s++){
        bf16x8 cur = *(const bf16x8*)(base + (size_t)s*DINNER);
        bf16x8 o;
        #pragma unroll
        for (int q=0;q<8;q++){
            float a = bias[q];
            a = fmaf((float)p3[q],  w4[q].x, a);
            a = fmaf((float)p2[q],  w4[q].y, a);
            a = fmaf((float)p1[q],  w4[q].z, a);
            a = fmaf((float)cur[q], w4[q].w, a);
            o[q] = (bf16)(a/(1.f+__expf(-a)));
        }
        *(bf16x8*)(outp + (size_t)s*DINNER) = o;
        p3 = p2; p2 = p1; p1 = cur;
    }
}

__device__ __forceinline__ float softplus_f(float a){
    return fmaxf(a, 0.f) + __logf(1.f + __expf(-fabsf(a)));
}

// pw[n] = p^(n+1), depth-4 multiply tree
__device__ __forceinline__ void powchain(float p, float* pw){
    pw[0]=p;
    pw[1]=pw[0]*pw[0];  pw[2]=pw[1]*pw[0];  pw[3]=pw[1]*pw[1];
    pw[4]=pw[1]*pw[2];  pw[5]=pw[2]*pw[2];  pw[6]=pw[2]*pw[3];  pw[7]=pw[3]*pw[3];
    pw[8]=pw[3]*pw[4];  pw[9]=pw[4]*pw[4];  pw[10]=pw[4]*pw[5]; pw[11]=pw[5]*pw[5];
    pw[12]=pw[5]*pw[6]; pw[13]=pw[6]*pw[6]; pw[14]=pw[6]*pw[7]; pw[15]=pw[7]*pw[7];
}

// ---------------- dt precompute: d-persistent threads, m-chunk loop; writes into dead xc ----------------
__global__ __launch_bounds__(256) void k_dt(const bf16* __restrict__ xdbl, const float* __restrict__ dtw,
                                            const float* __restrict__ dtb, bf16* __restrict__ dty){
    int d     = (blockIdx.x & 3)*256 + threadIdx.x;
    int mbase = (blockIdx.x >> 2)*DTMCH;
    float4 w[4];
    #pragma unroll
    for (int q=0;q<4;q++) w[q] = ((const float4*)(dtw + (size_t)d*16))[q];
    float bias = dtb[d];
    __shared__ __align__(16) bf16 xs[DTMCH][16];
    if (threadIdx.x < DTMCH*2){
        int r = threadIdx.x>>1, half = threadIdx.x&1;
        *(uint4*)&xs[r][half*8] = *(const uint4*)(xdbl + (size_t)(mbase+r)*48 + half*8);
    }
    __syncthreads();
    for (int s=0;s<DTMCH;s++){
        bf16x8 x0 = *(const bf16x8*)&xs[s][0];
        bf16x8 x1 = *(const bf16x8*)&xs[s][8];
        float a = bias;
        a=fmaf((float)x0[0],w[0].x,a); a=fmaf((float)x0[1],w[0].y,a);
        a=fmaf((float)x0[2],w[0].z,a); a=fmaf((float)x0[3],w[0].w,a);
        a=fmaf((float)x0[4],w[1].x,a); a=fmaf((float)x0[5],w[1].y,a);
        a=fmaf((float)x0[6],w[1].z,a); a=fmaf((float)x0[7],w[1].w,a);
        a=fmaf((float)x1[0],w[2].x,a); a=fmaf((float)x1[1],w[2].y,a);
        a=fmaf((float)x1[2],w[2].z,a); a=fmaf((float)x1[3],w[2].w,a);
        a=fmaf((float)x1[4],w[3].x,a); a=fmaf((float)x1[5],w[3].y,a);
        a=fmaf((float)x1[6],w[3].z,a); a=fmaf((float)x1[7],w[3].w,a);
        dty[(size_t)(mbase+s)*DINNER + d] = (bf16)softplus_f(a);
    }
}

// ---------------- scan pass 1: per-chunk (P,S); B staged fp32 in LDS ----------------
template<int LCHT>
__global__ __launch_bounds__(256) void k_pass1(const bf16* __restrict__ dty, const bf16* __restrict__ xa,
                                               const bf16* __restrict__ xdbl, const float* __restrict__ Alog,
                                               float* __restrict__ Pp, float* __restrict__ Sp, int nch){
    int d = blockIdx.x*256 + threadIdx.x;
    int c = blockIdx.y, b = blockIdx.z;
    int mbase = b*LL + c*LCHT;

    __shared__ __align__(16) float Bs[LCHT][16];
    for (int idx=threadIdx.x; idx<LCHT*2; idx+=256){
        int row = idx>>1, part = idx&1;
        bf16x8 v = *(const bf16x8*)(xdbl + (size_t)(mbase+row)*48 + 16 + part*8);
        #pragma unroll
        for (int q=0;q<8;q++) Bs[row][part*8+q] = (float)v[q];
    }
    bool st = true;
    float Ald[16];
    {
        const float4* Ap = (const float4*)(Alog + d*16);
        #pragma unroll
        for (int q=0;q<4;q++){
            float4 a4 = Ap[q];
            Ald[q*4+0]=a4.x; Ald[q*4+1]=a4.y; Ald[q*4+2]=a4.z; Ald[q*4+3]=a4.w;
        }
        #pragma unroll
        for (int n=0;n<16;n++) st = st && (fabsf(Ald[n]-LOGT[n]) < 1e-4f);
    }
    __syncthreads();

    float S[16];
    #pragma unroll
    for (int n=0;n<16;n++) S[n]=0.f;
    float sdt = 0.f;

    if (st){
        for (int s=0;s<LCHT;s++){
            int m = mbase + s;
            float dtv = (float)dty[(size_t)m*DINNER + d];
            float xv  = (float)xa [(size_t)m*DINNER + d];
            float dx  = dtv*xv;
            float pw[16];
            powchain(__expf(-dtv), pw);
            float4 b0 = *(const float4*)&Bs[s][0];
            float4 b1 = *(const float4*)&Bs[s][4];
            float4 b2 = *(const float4*)&Bs[s][8];
            float4 b3 = *(const float4*)&Bs[s][12];
            const float* bp = (const float*)&b0;   // b0..b3 contiguous? not guaranteed; use explicit
            S[0] = fmaf(pw[0], S[0], dx*b0.x);  S[1] = fmaf(pw[1], S[1], dx*b0.y);
            S[2] = fmaf(pw[2], S[2], dx*b0.z);  S[3] = fmaf(pw[3], S[3], dx*b0.w);
            S[4] = fmaf(pw[4], S[4], dx*b1.x);  S[5] = fmaf(pw[5], S[5], dx*b1.y);
            S[6] = fmaf(pw[6], S[6], dx*b1.z);  S[7] = fmaf(pw[7], S[7], dx*b1.w);
            S[8] = fmaf(pw[8], S[8], dx*b2.x);  S[9] = fmaf(pw[9], S[9], dx*b2.y);
            S[10]= fmaf(pw[10],S[10],dx*b2.z);  S[11]= fmaf(pw[11],S[11],dx*b2.w);
            S[12]= fmaf(pw[12],S[12],dx*b3.x);  S[13]= fmaf(pw[13],S[13],dx*b3.y);
            S[14]= fmaf(pw[14],S[14],dx*b3.z);  S[15]= fmaf(pw[15],S[15],dx*b3.w);
            (void)bp;
            sdt += dtv;
        }
    } else {
        float An[16];
        #pragma unroll
        for (int n=0;n<16;n++) An[n] = -__expf(Ald[n]);
        for (int s=0;s<LCHT;s++){
            int m = mbase + s;
            float dtv = (float)dty[(size_t)m*DINNER + d];
            float xv  = (float)xa [(size_t)m*DINNER + d];
            float dx  = dtv*xv;
            #pragma unroll
            for (int n=0;n<16;n++)
                S[n] = fmaf(__expf(dtv*An[n]), S[n], dx*Bs[s][n]);
            sdt += dtv;
        }
    }
    size_t base = ((size_t)(b*nch + c)*DINNER + d)*16;
    float P[16];
    if (st){
        powchain(__expf(-sdt), P);
    } else {
        float An[16];
        #pragma unroll
        for (int n=0;n<16;n++) An[n] = -__expf(Ald[n]);
        #pragma unroll
        for (int n=0;n<16;n++) P[n] = __expf(An[n]*sdt);
    }
    #pragma unroll
    for (int q=0;q<4;q++){
        *(float4*)&Pp[base+q*4] = make_float4(P[q*4],P[q*4+1],P[q*4+2],P[q*4+3]);
        *(float4*)&Sp[base+q*4] = make_float4(S[q*4],S[q*4+1],S[q*4+2],S[q*4+3]);
    }
}

// ---------------- scan pass 2: cross-chunk prefix; h into P slot ----------------
__global__ __launch_bounds__(256) void k_pass2(float* __restrict__ Pp, float* __restrict__ Sp, int nch){
    int i = blockIdx.x*256 + threadIdx.x;
    int b   = i >> 14;
    int low = i & 16383;
    float h = 0.f;
    for (int c=0;c<nch;c++){
        size_t idx = (size_t)(b*nch + c)*16384 + low;
        float P = Pp[idx], S = Sp[idx];
        Pp[idx] = h;
        h = P*h + S;
    }
}

// ---------------- scan pass 3: replay; B,C staged fp32; y over dt buffer ----------------
template<int LCHT>
__global__ __launch_bounds__(256) void k_pass3(bf16* __restrict__ dty, const bf16* __restrict__ xa,
                                               const bf16* __restrict__ xdbl, const bf16* __restrict__ z,
                                               const float* __restrict__ Alog, const float* __restrict__ Dp,
                                               const float* __restrict__ Pp, int nch){
    int d = blockIdx.x*256 + threadIdx.x;
    int c = blockIdx.y, b = blockIdx.z;
    int mbase = b*LL + c*LCHT;

    __shared__ __align__(16) float BCs[LCHT][32];   // 0-15 B, 16-31 C (fp32)
    for (int idx=threadIdx.x; idx<LCHT*4; idx+=256){
        int row = idx>>2, part = idx&3;
        bf16x8 v = *(const bf16x8*)(xdbl + (size_t)(mbase+row)*48 + 16 + part*8);
        #pragma unroll
        for (int q=0;q<8;q++) BCs[row][part*8+q] = (float)v[q];
    }
    bool st = true;
    float Ald[16];
    {
        const float4* Ap = (const float4*)(Alog + d*16);
        #pragma unroll
        for (int q=0;q<4;q++){
            float4 a4 = Ap[q];
            Ald[q*4+0]=a4.x; Ald[q*4+1]=a4.y; Ald[q*4+2]=a4.z; Ald[q*4+3]=a4.w;
        }
        #pragma unroll
        for (int n=0;n<16;n++) st = st && (fabsf(Ald[n]-LOGT[n]) < 1e-4f);
    }
    float h[16];
    size_t hbase = ((size_t)(b*nch + c)*DINNER + d)*16;
    #pragma unroll
    for (int q=0;q<4;q++){
        float4 h4 = *(const float4*)&Pp[hbase+q*4];
        h[q*4]=h4.x; h[q*4+1]=h4.y; h[q*4+2]=h4.z; h[q*4+3]=h4.w;
    }
    float Dd = Dp[d];
    __syncthreads();

    if (st){
        for (int s=0;s<LCHT;s++){
            int m = mbase + s;
            size_t off = (size_t)m*DINNER + d;
            float dtv = (float)dty[off];
            float xv  = (float)xa[off];
            float zv  = (float)z[off];
            float dx  = dtv*xv;
            float pw[16];
            powchain(__expf(-dtv), pw);
            float4 b0 = *(const float4*)&BCs[s][0];
            float4 b1 = *(const float4*)&BCs[s][4];
            float4 b2 = *(const float4*)&BCs[s][8];
            float4 b3 = *(const float4*)&BCs[s][12];
            float4 c0 = *(const float4*)&BCs[s][16];
            float4 c1 = *(const float4*)&BCs[s][20];
            float4 c2 = *(const float4*)&BCs[s][24];
            float4 c3 = *(const float4*)&BCs[s][28];
            float yv = 0.f;
            h[0] = fmaf(pw[0], h[0], dx*b0.x);  yv = fmaf(h[0], c0.x, yv);
            h[1] = fmaf(pw[1], h[1], dx*b0.y);  yv = fmaf(h[1], c0.y, yv);
            h[2] = fmaf(pw[2], h[2], dx*b0.z);  yv = fmaf(h[2], c0.z, yv);
            h[3] = fmaf(pw[3], h[3], dx*b0.w);  yv = fmaf(h[3], c0.w, yv);
            h[4] = fmaf(pw[4], h[4], dx*b1.x);  yv = fmaf(h[4], c1.x, yv);
            h[5] = fmaf(pw[5], h[5], dx*b1.y);  yv = fmaf(h[5], c1.y, yv);
            h[6] = fmaf(pw[6], h[6], dx*b1.z);  yv = fmaf(h[6], c1.z, yv);
            h[7] = fmaf(pw[7], h[7], dx*b1.w);  yv = fmaf(h[7], c1.w, yv);
            h[8] = fmaf(pw[8], h[8], dx*b2.x);  yv = fmaf(h[8], c2.x, yv);
            h[9] = fmaf(pw[9], h[9], dx*b2.y);  yv = fmaf(h[9], c2.y, yv);
            h[10]= fmaf(pw[10],h[10],dx*b2.z);  yv = fmaf(h[10],c2.z, yv);
            h[11]= fmaf(pw[11],h[11],dx*b2.w);  yv = fmaf(h[11],c2.w, yv);
            h[12]= fmaf(pw[12],h[12],dx*b3.x);  yv = fmaf(h[12],c3.x, yv);
            h[13]= fmaf(pw[13],h[13],dx*b3.y);  yv = fmaf(h[13],c3.y, yv);
            h[14]= fmaf(pw[14],h[14],dx*b3.z);  yv = fmaf(h[14],c3.z, yv);
            h[15]= fmaf(pw[15],h[15],dx*b3.w);  yv = fmaf(h[15],c3.w, yv);
            float g = zv/(1.f+__expf(-zv));
            dty[off] = (bf16)((yv + xv*Dd)*g);
        }
    } else {
        float An[16];
        #pragma unroll
        for (int n=0;n<16;n++) An[n] = -__expf(Ald[n]);
        for (int s=0;s<LCHT;s++){
            int m = mbase + s;
            size_t off = (size_t)m*DINNER + d;
            float dtv = (float)dty[off];
            float xv  = (float)xa[off];
            float zv  = (float)z[off];
            float dx  = dtv*xv;
            float yv = 0.f;
            #pragma unroll
            for (int n=0;n<16;n++){
                h[n] = fmaf(__expf(dtv*An[n]), h[n], dx*BCs[s][n]);
                yv   = fmaf(h[n], BCs[s][16+n], yv);
            }
            float g = zv/(1.f+__expf(-zv));
            dty[off] = (bf16)((yv + xv*Dd)*g);
        }
    }
}

extern "C" void kernel_launch(void* const* d_in, const int* in_sizes, int n_in,
                              void* d_out, int out_size, void* d_ws, size_t ws_size,
                              hipStream_t stream) {
    const float* x     = (const float*)d_in[0];
    const float* normw = (const float*)d_in[1];
    const float* w_in  = (const float*)d_in[2];
    const float* convw = (const float*)d_in[3];
    const float* convb = (const float*)d_in[4];
    const float* w_xp  = (const float*)d_in[5];
    const float* dtw   = (const float*)d_in[6];
    const float* dtb   = (const float*)d_in[7];
    const float* Alog  = (const float*)d_in[8];
    const float* Dp    = (const float*)d_in[9];
    const float* w_out = (const float*)d_in[10];

    const size_t WB    = ((size_t)2048*256 + 48*1024 + 256*1024)*2;
    const size_t WB_AL = (WB + 255) & ~(size_t)255;
    auto need = [WB_AL](int nb, int nch)->size_t{
        size_t rows = (size_t)nb*LL;
        size_t big  = rows*DINNER*2;
        size_t xd   = ((rows*48*2) + 255) & ~(size_t)255;
        size_t ps   = (size_t)nb*nch*DINNER*16*8;
        return WB_AL + 3*big + xd + ps;
    };
    const int cands[8][2] = {{8,128},{8,64},{4,128},{4,64},{2,128},{2,64},{1,128},{1,64}};
    int NB = 0, NCHv = 0;
    for (int k=0;k<8;k++) if (need(cands[k][0], cands[k][1]) <= ws_size){ NB=cands[k][0]; NCHv=cands[k][1]; break; }
    if (!NB){
        k_wsfail<<<(out_size+255)/256, 256, 0, stream>>>((float*)d_out, out_size);
        return;
    }
    const int LCHv = LL/NCHv;

    char* ws = (char*)d_ws;
    bf16* win_b  = (bf16*)ws;
    bf16* wxp_b  = (bf16*)(ws + (size_t)2048*256*2);
    bf16* wout_b = (bf16*)(ws + (size_t)2048*256*2 + (size_t)48*1024*2);

    size_t rows  = (size_t)NB*LL;
    size_t big   = rows*DINNER*2;
    size_t xd_al = ((rows*48*2) + 255) & ~(size_t)255;
    char*  ar    = ws + WB_AL;
    bf16*  xcy   = (bf16*)ar;            // xc -> dt -> y (sequential lifetimes)
    bf16*  zb    = (bf16*)(ar + big);
    bf16*  xab   = (bf16*)(ar + 2*big);
    bf16*  xdb   = (bf16*)(ar + 3*big);
    float* Pp    = (float*)(ar + 3*big + xd_al);
    float* Sp    = Pp + (size_t)NB*NCHv*DINNER*16;
    bf16*  hb    = (bf16*)Pp;            // overlaps PS (disjoint lifetimes)

    k_cast3<<<(2048*256 + 48*1024 + 256*1024)/256, 256, 0, stream>>>(
        w_in, w_xp, w_out, win_b, wxp_b, wout_b, 2048*256, 48*1024, 256*1024);

    for (int b0=0; b0<BB; b0+=NB){
        const float* xb = x + (size_t)b0*LL*DMODEL;
        float*       ob = (float*)d_out + (size_t)b0*LL*DMODEL;
        k_rms<<<(int)rows, 256, 0, stream>>>(xb, normw, hb);
        k_gemm<1,false><<<dim3((int)rows/128, 16), 256, 0, stream>>>(
            hb, win_b, xcy, zb, nullptr, nullptr, (int)rows, 2048, 256);
        k_conv<<<(int)(rows/(CT*2)), 256, 0, stream>>>(xcy, convw, convb, xab);
        k_gemm<0,true><<<dim3((int)rows/128, 1), 256, 0, stream>>>(
            xab, wxp_b, xdb, nullptr, nullptr, nullptr, (int)rows, 48, 1024);
        k_dt<<<(int)(rows/DTMCH)*4, 256, 0, stream>>>(xdb, dtw, dtb, xcy);
        if (LCHv == 64){
            k_pass1<64><<<dim3(4, NCHv, NB), 256, 0, stream>>>(xcy, xab, xdb, Alog, Pp, Sp, NCHv);
            k_pass2<<<NB*64, 256, 0, stream>>>(Pp, Sp, NCHv);
            k_pass3<64><<<dim3(4, NCHv, NB), 256, 0, stream>>>(xcy, xab, xdb, zb, Alog, Dp, Pp, NCHv);
        } else {
            k_pass1<32><<<dim3(4, NCHv, NB), 256, 0, stream>>>(xcy, xab, xdb, Alog, Pp, Sp, NCHv);
            k_pass2<<<NB*64, 256, 0, stream>>>(Pp, Sp, NCHv);
            k_pass3<32><<<dim3(4, NCHv, NB), 256, 0, stream>>>(xcy, xab, xdb, zb, Alog, Dp, Pp, NCHv);
        }
        k_gemm<2,false><<<dim3((int)rows/128, 2), 256, 0, stream>>>(
            xcy, wout_b, nullptr, nullptr, ob, xb, (int)rows, 256, 1024);
    }
}